// Round 1
// baseline (379.983 us; speedup 1.0000x reference)
//
#include <hip/hip_runtime.h>
#include <stdint.h>

#define SHIFT 4
#define EPS 1e-5f

#define B_ 8
#define C_ 256
#define H_ 128
#define W_ 128
#define HW_ (H_*W_)
#define NPIX (B_*H_*W_)      // 131072 pixels
#define NWIN 2048            // 8 * 16 * 16 windows
#define NTOK (NWIN*64)       // 131072 token rows

typedef unsigned short u16;
typedef float f32x4 __attribute__((ext_vector_type(4)));
typedef __bf16 bf16x8 __attribute__((ext_vector_type(8)));
typedef unsigned short u16x8 __attribute__((ext_vector_type(8)));
typedef uint32_t u32x4 __attribute__((ext_vector_type(4)));

static __device__ __forceinline__ u16 f2bf(float f) {
    uint32_t u = __builtin_bit_cast(uint32_t, f);
    u = u + 0x7fffu + ((u >> 16) & 1u);
    return (u16)(u >> 16);
}
static __device__ __forceinline__ float bf2f(u16 u) {
    return __builtin_bit_cast(float, (uint32_t)u << 16);
}

// ---------------- K0: weight transpose+convert ----------------
__global__ void k_prep_w(const float* __restrict__ wqkv, const float* __restrict__ wproj,
                         u16* __restrict__ wqkvT, u16* __restrict__ wprojT) {
    int i = blockIdx.x * blockDim.x + threadIdx.x;
    if (i < 768 * 256) {
        int n = i >> 8, k = i & 255;
        wqkvT[i] = f2bf(wqkv[k * 768 + n]);
    } else {
        int j = i - 768 * 256;   // < 65536
        int n = j >> 8, k = j & 255;
        wprojT[j] = f2bf(wproj[k * 256 + n]);
    }
}

// ---------------- K1: per-pixel LN stats ----------------
__global__ __launch_bounds__(256) void k_stats(const float* __restrict__ x,
                                               float* __restrict__ mean,
                                               float* __restrict__ rstd) {
    int p = blockIdx.x * 256 + threadIdx.x;      // b*16384 + h*128 + w
    int b = p >> 14;
    int hw = p & 16383;
    const float* px = x + (size_t)b * C_ * HW_ + hw;
    float s = 0.f, ss = 0.f;
    #pragma unroll 8
    for (int c = 0; c < C_; ++c) {
        float v = px[(size_t)c * HW_];
        s += v; ss += v * v;
    }
    float m = s * (1.f / C_);
    float var = ss * (1.f / C_) - m * m;
    mean[p] = m;
    rstd[p] = rsqrtf(var + EPS);
}

// ---------------- K2: LN + shift + window partition -> y_win[131072][256] bf16 ----------------
// grid (4 ctiles, 128 h', 8 b), block 256
__global__ __launch_bounds__(256) void k_ln_win(const float* __restrict__ x,
                                                const float* __restrict__ mean,
                                                const float* __restrict__ rstd,
                                                const float* __restrict__ g,
                                                const float* __restrict__ beta,
                                                u16* __restrict__ ywin) {
    __shared__ float tile[64][129];
    int ct = blockIdx.x;
    int hp = blockIdx.y;
    int b  = blockIdx.z;
    int hs = (hp + SHIFT) & 127;
    int t = threadIdx.x;
    int c0 = ct * 64;
    const float* xb = x + ((size_t)b * C_ + c0) * HW_ + hs * W_;
    const float* mrow = mean + (b * H_ + hs) * W_;
    const float* rrow = rstd + (b * H_ + hs) * W_;
    #pragma unroll 4
    for (int i = 0; i < 32; ++i) {
        int e = i * 256 + t;
        int cl = e >> 7;
        int wp = e & 127;
        int wsx = (wp + SHIFT) & 127;
        float v = xb[(size_t)cl * HW_ + wsx];
        int c = c0 + cl;
        tile[cl][wp] = (v - mrow[wsx]) * rrow[wsx] * g[c] + beta[c];
    }
    __syncthreads();
    int wh = hp >> 3, r = hp & 7;
    #pragma unroll 4
    for (int i = 0; i < 32; ++i) {
        int e = i * 256 + t;
        int wp = e >> 6;
        int cl = e & 63;
        int ww = wp >> 3, s = wp & 7;
        int win = (b * 16 + wh) * 16 + ww;
        int row = win * 64 + r * 8 + s;
        ywin[(size_t)row * C_ + c0 + cl] = f2bf(tile[cl][wp]);
    }
}

// ---------------- GEMM: A[M][256] bf16 @ BtT[N][256] bf16 ----------------
// 128x128 tile, BK=32, 4 waves (2x2), per-wave 64x64 via 4x4 frags of 16x16x32
template<int EPI>
__global__ __launch_bounds__(256) void k_gemm(const u16* __restrict__ A,
                                              const u16* __restrict__ Bt,
                                              const float* __restrict__ bias,
                                              u16* __restrict__ qp, u16* __restrict__ kp,
                                              u16* __restrict__ vp, u16* __restrict__ yl,
                                              int M, int N) {
    __shared__ __align__(16) u16 Al[128 * 32];
    __shared__ __align__(16) u16 Bl[128 * 32];
    const int K = 256;
    int tiles_n = N >> 7;
    int m0 = (blockIdx.x / tiles_n) << 7;
    int n0 = (blockIdx.x % tiles_n) << 7;
    int t = threadIdx.x;
    int wave = t >> 6, lane = t & 63;
    int wm = wave >> 1, wn = wave & 1;
    int lr = lane & 15, lk = lane >> 4;

    const f32x4 fz = {0.f, 0.f, 0.f, 0.f};
    f32x4 acc[4][4];
    #pragma unroll
    for (int i = 0; i < 4; ++i)
        #pragma unroll
        for (int j = 0; j < 4; ++j) acc[i][j] = fz;

    for (int k0 = 0; k0 < K; k0 += 32) {
        __syncthreads();
        #pragma unroll
        for (int sgm = 0; sgm < 2; ++sgm) {
            int L = (sgm * 256 + t) * 16;     // byte offset within 8 KiB tile
            int row = L >> 6;
            int cb = L & 63;
            u32x4 va = *(const u32x4*)((const char*)A + (((size_t)(m0 + row)) * K + k0) * 2 + cb);
            *(u32x4*)((char*)Al + L) = va;
            u32x4 vb = *(const u32x4*)((const char*)Bt + (((size_t)(n0 + row)) * K + k0) * 2 + cb);
            *(u32x4*)((char*)Bl + L) = vb;
        }
        __syncthreads();
        bf16x8 af[4], bfr[4];
        #pragma unroll
        for (int i = 0; i < 4; ++i) {
            int row = wm * 64 + i * 16 + lr;
            af[i] = __builtin_bit_cast(bf16x8, *(const u16x8*)(&Al[row * 32 + lk * 8]));
        }
        #pragma unroll
        for (int j = 0; j < 4; ++j) {
            int row = wn * 64 + j * 16 + lr;
            bfr[j] = __builtin_bit_cast(bf16x8, *(const u16x8*)(&Bl[row * 32 + lk * 8]));
        }
        #pragma unroll
        for (int i = 0; i < 4; ++i)
            #pragma unroll
            for (int j = 0; j < 4; ++j)
                acc[i][j] = __builtin_amdgcn_mfma_f32_16x16x32_bf16(af[i], bfr[j], acc[i][j], 0, 0, 0);
    }

    int baserow = m0 + wm * 64;
    int basecol = n0 + wn * 64;
    if (EPI == 0) {
        // scatter qkv -> [win][head][n][d] bf16 (q, k, v separate bases)
        #pragma unroll
        for (int i = 0; i < 4; ++i)
            #pragma unroll
            for (int j = 0; j < 4; ++j) {
                int col = basecol + j * 16 + lr;
                int which = col >> 8, rem = col & 255;
                int head = rem >> 5, d = rem & 31;
                u16* dst = (which == 0) ? qp : (which == 1) ? kp : vp;
                float bi = bias[col];
                #pragma unroll
                for (int rg = 0; rg < 4; ++rg) {
                    int row = baserow + i * 16 + lk * 4 + rg;
                    int win = row >> 6, n = row & 63;
                    dst[(((size_t)win * 8 + head) * 64 + n) * 32 + d] = f2bf(acc[i][j][rg] + bi);
                }
            }
    } else {
        // proj epilogue: un-window + un-shift -> y_lin[b][h][w][c] bf16
        #pragma unroll
        for (int i = 0; i < 4; ++i)
            #pragma unroll
            for (int rg = 0; rg < 4; ++rg) {
                int row = baserow + i * 16 + lk * 4 + rg;
                int win = row >> 6, n = row & 63;
                int b = win >> 8, wh = (win >> 4) & 15, ww = win & 15;
                int r = n >> 3, s = n & 7;
                int h = (wh * 8 + r + SHIFT) & 127;
                int w = (ww * 8 + s + SHIFT) & 127;
                size_t base = (((size_t)b * H_ + h) * W_ + w) * C_;
                #pragma unroll
                for (int j = 0; j < 4; ++j) {
                    int col = basecol + j * 16 + lr;
                    yl[base + col] = f2bf(acc[i][j][rg] + bias[col]);
                }
            }
    }
}

// ---------------- K4: windowed attention, 1 wave per (win, head) ----------------
__global__ __launch_bounds__(64) void k_attn(const u16* __restrict__ q,
                                             const u16* __restrict__ kk,
                                             const u16* __restrict__ v,
                                             u16* __restrict__ o) {
    __shared__ __align__(16) u16 P[64 * 72];
    __shared__ __align__(16) u16 Vt[32 * 64];
    int wh = blockIdx.x;                 // win*8 + head
    int lane = threadIdx.x;
    int lr = lane & 15, lk = lane >> 4;
    const u16* qb = q + (size_t)wh * 2048;
    const u16* kb = kk + (size_t)wh * 2048;
    const u16* vb = v + (size_t)wh * 2048;

    // Vt[d][n] = v[n][d]
    #pragma unroll
    for (int dc = 0; dc < 4; ++dc) {
        u16x8 vv = *(const u16x8*)(vb + lane * 32 + dc * 8);
        #pragma unroll
        for (int jj = 0; jj < 8; ++jj) Vt[(dc * 8 + jj) * 64 + lane] = vv[jj];
    }

    const f32x4 fz = {0.f, 0.f, 0.f, 0.f};
    f32x4 sacc[4][4];
    #pragma unroll
    for (int i = 0; i < 4; ++i)
        #pragma unroll
        for (int j = 0; j < 4; ++j) sacc[i][j] = fz;

    bf16x8 qf[4], kf[4];
    #pragma unroll
    for (int i = 0; i < 4; ++i)
        qf[i] = __builtin_bit_cast(bf16x8, *(const u16x8*)(qb + (i * 16 + lr) * 32 + lk * 8));
    #pragma unroll
    for (int j = 0; j < 4; ++j)
        kf[j] = __builtin_bit_cast(bf16x8, *(const u16x8*)(kb + (j * 16 + lr) * 32 + lk * 8));
    #pragma unroll
    for (int i = 0; i < 4; ++i)
        #pragma unroll
        for (int j = 0; j < 4; ++j)
            sacc[i][j] = __builtin_amdgcn_mfma_f32_16x16x32_bf16(qf[i], kf[j], sacc[i][j], 0, 0, 0);

    const float scale = 0.17677669529663687f;   // 32^-0.5
    #pragma unroll
    for (int i = 0; i < 4; ++i) {
        #pragma unroll
        for (int rg = 0; rg < 4; ++rg) {
            float s0 = sacc[i][0][rg] * scale, s1 = sacc[i][1][rg] * scale;
            float s2 = sacc[i][2][rg] * scale, s3 = sacc[i][3][rg] * scale;
            float mx = fmaxf(fmaxf(s0, s1), fmaxf(s2, s3));
            mx = fmaxf(mx, __shfl_xor(mx, 1));
            mx = fmaxf(mx, __shfl_xor(mx, 2));
            mx = fmaxf(mx, __shfl_xor(mx, 4));
            mx = fmaxf(mx, __shfl_xor(mx, 8));
            float p0 = __expf(s0 - mx), p1 = __expf(s1 - mx);
            float p2 = __expf(s2 - mx), p3 = __expf(s3 - mx);
            float sm = p0 + p1 + p2 + p3;
            sm += __shfl_xor(sm, 1);
            sm += __shfl_xor(sm, 2);
            sm += __shfl_xor(sm, 4);
            sm += __shfl_xor(sm, 8);
            float rs = 1.f / sm;
            int row = i * 16 + lk * 4 + rg;
            P[row * 72 + 0 * 16 + lr] = f2bf(p0 * rs);
            P[row * 72 + 1 * 16 + lr] = f2bf(p1 * rs);
            P[row * 72 + 2 * 16 + lr] = f2bf(p2 * rs);
            P[row * 72 + 3 * 16 + lr] = f2bf(p3 * rs);
        }
    }
    __syncthreads();

    f32x4 oacc[4][2];
    #pragma unroll
    for (int i = 0; i < 4; ++i)
        #pragma unroll
        for (int j = 0; j < 2; ++j) oacc[i][j] = fz;
    #pragma unroll
    for (int ks = 0; ks < 2; ++ks) {
        bf16x8 pf[4], vf[2];
        #pragma unroll
        for (int i = 0; i < 4; ++i)
            pf[i] = __builtin_bit_cast(bf16x8, *(const u16x8*)(&P[(i * 16 + lr) * 72 + ks * 32 + lk * 8]));
        #pragma unroll
        for (int j = 0; j < 2; ++j)
            vf[j] = __builtin_bit_cast(bf16x8, *(const u16x8*)(&Vt[(j * 16 + lr) * 64 + ks * 32 + lk * 8]));
        #pragma unroll
        for (int i = 0; i < 4; ++i)
            #pragma unroll
            for (int j = 0; j < 2; ++j)
                oacc[i][j] = __builtin_amdgcn_mfma_f32_16x16x32_bf16(pf[i], vf[j], oacc[i][j], 0, 0, 0);
    }
    int win = wh >> 3, head = wh & 7;
    #pragma unroll
    for (int i = 0; i < 4; ++i)
        #pragma unroll
        for (int j = 0; j < 2; ++j)
            #pragma unroll
            for (int rg = 0; rg < 4; ++rg) {
                int qr = i * 16 + lk * 4 + rg;
                o[((size_t)win * 64 + qr) * 256 + head * 32 + j * 16 + lr] = f2bf(oacc[i][j][rg]);
            }
}

// ---------------- K6: out[b][c][h][w] = 2*(y_lin[b][h][w][c] + x[b][c][h][w]) ----------------
// grid (32 = wtile*8+ctile, 128 h, 8 b), block 256
__global__ __launch_bounds__(256) void k_final(const u16* __restrict__ ylin,
                                               const float* __restrict__ x,
                                               float* __restrict__ out) {
    __shared__ float tl[32][33];
    int bx = blockIdx.x;
    int wt = bx >> 3, ct = bx & 7;
    int h = blockIdx.y, b = blockIdx.z;
    int t = threadIdx.x;
    #pragma unroll
    for (int i = 0; i < 4; ++i) {
        int wl = i * 8 + (t >> 5);
        int c = t & 31;
        tl[wl][c] = bf2f(ylin[(((size_t)b * H_ + h) * W_ + wt * 32 + wl) * C_ + ct * 32 + c]);
    }
    __syncthreads();
    #pragma unroll
    for (int i = 0; i < 4; ++i) {
        int cl = i * 8 + (t >> 5);
        int wl = t & 31;
        size_t oi = (((size_t)b * C_ + ct * 32 + cl) * H_ + h) * W_ + wt * 32 + wl;
        out[oi] = 2.f * (tl[wl][cl] + x[oi]);
    }
}

extern "C" void kernel_launch(void* const* d_in, const int* in_sizes, int n_in,
                              void* d_out, int out_size, void* d_ws, size_t ws_size,
                              hipStream_t stream) {
    const float* x     = (const float*)d_in[0];
    const float* g1    = (const float*)d_in[1];
    const float* bb1   = (const float*)d_in[2];
    const float* wqkv  = (const float*)d_in[3];
    const float* bqkv  = (const float*)d_in[4];
    const float* wproj = (const float*)d_in[5];
    const float* bproj = (const float*)d_in[6];
    float* out = (float*)d_out;

    char* ws = (char*)d_ws;
    float* mean  = (float*)ws;                                   // 512 KiB
    float* rstd  = (float*)(ws + (512 << 10));                   // 512 KiB
    u16* wqkvT   = (u16*)(ws + (1 << 20));                       // 384 KiB
    u16* wprojT  = (u16*)(ws + (1 << 20) + (384 << 10));         // 128 KiB
    u16* ywin    = (u16*)(ws + (2ull << 20));                    // 64 MiB  [2,66)
    u16* obuf    = ywin;                                         // alias (ywin dead after K3... reused in K4)
    u16* vbuf    = (u16*)(ws + (2ull << 20) + (64ull << 20));    // 64 MiB  [66,130)
    u16* ylin    = vbuf;                                         // alias (v dead after K4)
    u16* qbuf    = (u16*)d_out;                                  // d_out as scratch: q 64 MiB
    u16* kbuf    = qbuf + (size_t)NTOK * 256;                    // k 64 MiB

    k_prep_w<<<1024, 256, 0, stream>>>(wqkv, wproj, wqkvT, wprojT);
    k_stats<<<NPIX / 256, 256, 0, stream>>>(x, mean, rstd);
    k_ln_win<<<dim3(4, 128, 8), 256, 0, stream>>>(x, mean, rstd, g1, bb1, ywin);
    k_gemm<0><<<(NTOK / 128) * 6, 256, 0, stream>>>(ywin, wqkvT, bqkv, qbuf, kbuf, vbuf, nullptr, NTOK, 768);
    k_attn<<<NWIN * 8, 64, 0, stream>>>(qbuf, kbuf, vbuf, obuf);
    k_gemm<1><<<(NTOK / 128) * 2, 256, 0, stream>>>(obuf, wprojT, bproj, nullptr, nullptr, nullptr, ylin, NTOK, 256);
    k_final<<<dim3(32, 128, 8), 256, 0, stream>>>(ylin, x, out);
}

// Round 2
// 320.149 us; speedup vs baseline: 1.1869x; 1.1869x over previous
//
#include <hip/hip_runtime.h>
#include <stdint.h>

#define SHIFT 4
#define EPS 1e-5f

#define B_ 8
#define C_ 256
#define H_ 128
#define W_ 128
#define HW_ (H_*W_)
#define NPIX (B_*H_*W_)      // 131072 pixels
#define NWIN 2048            // 8 * 16 * 16 windows
#define NTOK (NWIN*64)       // 131072 token rows

typedef unsigned short u16;
typedef float f32x4 __attribute__((ext_vector_type(4)));
typedef __bf16 bf16x8 __attribute__((ext_vector_type(8)));
typedef unsigned short u16x8 __attribute__((ext_vector_type(8)));
typedef uint32_t u32x4 __attribute__((ext_vector_type(4)));

#define GLOAD16(gp, lp) __builtin_amdgcn_global_load_lds( \
    (const __attribute__((address_space(1))) uint32_t*)(gp), \
    (__attribute__((address_space(3))) uint32_t*)(lp), 16, 0, 0)

static __device__ __forceinline__ u16 f2bf(float f) {
    uint32_t u = __builtin_bit_cast(uint32_t, f);
    u = u + 0x7fffu + ((u >> 16) & 1u);
    return (u16)(u >> 16);
}
static __device__ __forceinline__ float bf2f(u16 u) {
    return __builtin_bit_cast(float, (uint32_t)u << 16);
}

// ---------------- K0: weight transpose+convert ----------------
__global__ void k_prep_w(const float* __restrict__ wqkv, const float* __restrict__ wproj,
                         u16* __restrict__ wqkvT, u16* __restrict__ wprojT) {
    int i = blockIdx.x * blockDim.x + threadIdx.x;
    if (i < 768 * 256) {
        int n = i >> 8, k = i & 255;
        wqkvT[i] = f2bf(wqkv[k * 768 + n]);
    } else {
        int j = i - 768 * 256;   // < 65536
        int n = j >> 8, k = j & 255;
        wprojT[j] = f2bf(wproj[k * 256 + n]);
    }
}

// ---------------- K1: per-pixel LN stats ----------------
__global__ __launch_bounds__(256) void k_stats(const float* __restrict__ x,
                                               float* __restrict__ mean,
                                               float* __restrict__ rstd) {
    int p = blockIdx.x * 256 + threadIdx.x;      // b*16384 + h*128 + w
    int b = p >> 14;
    int hw = p & 16383;
    const float* px = x + (size_t)b * C_ * HW_ + hw;
    float s = 0.f, ss = 0.f;
    #pragma unroll 8
    for (int c = 0; c < C_; ++c) {
        float v = px[(size_t)c * HW_];
        s += v; ss += v * v;
    }
    float m = s * (1.f / C_);
    float var = ss * (1.f / C_) - m * m;
    mean[p] = m;
    rstd[p] = rsqrtf(var + EPS);
}

// ---------------- K2: LN + shift + window partition -> y_win[131072][256] bf16 ----------------
__global__ __launch_bounds__(256) void k_ln_win(const float* __restrict__ x,
                                                const float* __restrict__ mean,
                                                const float* __restrict__ rstd,
                                                const float* __restrict__ g,
                                                const float* __restrict__ beta,
                                                u16* __restrict__ ywin) {
    __shared__ float tile[64][129];
    int ct = blockIdx.x;
    int hp = blockIdx.y;
    int b  = blockIdx.z;
    int hs = (hp + SHIFT) & 127;
    int t = threadIdx.x;
    int c0 = ct * 64;
    const float* xb = x + ((size_t)b * C_ + c0) * HW_ + hs * W_;
    const float* mrow = mean + (b * H_ + hs) * W_;
    const float* rrow = rstd + (b * H_ + hs) * W_;
    #pragma unroll 4
    for (int i = 0; i < 32; ++i) {
        int e = i * 256 + t;
        int cl = e >> 7;
        int wp = e & 127;
        int wsx = (wp + SHIFT) & 127;
        float v = xb[(size_t)cl * HW_ + wsx];
        int c = c0 + cl;
        tile[cl][wp] = (v - mrow[wsx]) * rrow[wsx] * g[c] + beta[c];
    }
    __syncthreads();
    int wh = hp >> 3, r = hp & 7;
    #pragma unroll 4
    for (int i = 0; i < 32; ++i) {
        int e = i * 256 + t;
        int wp = e >> 6;
        int cl = e & 63;
        int ww = wp >> 3, s = wp & 7;
        int win = (b * 16 + wh) * 16 + ww;
        int row = win * 64 + r * 8 + s;
        ywin[(size_t)row * C_ + c0 + cl] = f2bf(tile[cl][wp]);
    }
}

// ---------------- GEMM: A[M][256] bf16 @ Bt[N][256] bf16 ----------------
// m97 structure: 128x128 tile, BK=32, 4 waves (2x2), global_load_lds w16 staging,
// XCD-aware block swizzle for A-panel L2 reuse.
template<int EPI>
__global__ __launch_bounds__(256) void k_gemm(const u16* __restrict__ A,
                                              const u16* __restrict__ Bt,
                                              const float* __restrict__ bias,
                                              u16* __restrict__ qp, u16* __restrict__ kp,
                                              u16* __restrict__ vp, u16* __restrict__ yl,
                                              int M, int N) {
    __shared__ __align__(16) u16 Al[128 * 32];
    __shared__ __align__(16) u16 Bl[128 * 32];
    int tiles_n = N >> 7;
    // XCD swizzle: consecutive logical tiles (same m, all n) on one XCD
    int nwg = gridDim.x;
    int bid = blockIdx.x;
    int swz = (bid & 7) * (nwg >> 3) + (bid >> 3);
    int m0 = (swz / tiles_n) << 7;
    int n0 = (swz % tiles_n) << 7;
    int t = threadIdx.x;
    int wave = t >> 6, lane = t & 63;
    int wm = wave >> 1, wn = wave & 1;
    int lr = lane & 15, lk = lane >> 4;
    // staging address decomposition: LDS linear = sgm*4096 + wave*1024 + lane*16 bytes
    int srow = (wave << 4) + (lane >> 2);    // row within 64-row half
    int scol = (lane & 3) << 3;              // u16 element offset in row

    const f32x4 fz = {0.f, 0.f, 0.f, 0.f};
    f32x4 acc[4][4];
    #pragma unroll
    for (int i = 0; i < 4; ++i)
        #pragma unroll
        for (int j = 0; j < 4; ++j) acc[i][j] = fz;

    const u16* gA = A + ((size_t)(m0 + srow) << 8) + scol;
    const u16* gB = Bt + ((size_t)(n0 + srow) << 8) + scol;
    char* lA = (char*)Al + wave * 1024;
    char* lB = (char*)Bl + wave * 1024;

    for (int k0 = 0; k0 < 256; k0 += 32) {
        __syncthreads();
        GLOAD16(gA + k0, lA);
        GLOAD16(gA + k0 + (64 << 8), lA + 4096);
        GLOAD16(gB + k0, lB);
        GLOAD16(gB + k0 + (64 << 8), lB + 4096);
        __syncthreads();
        bf16x8 af[4], bfr[4];
        #pragma unroll
        for (int i = 0; i < 4; ++i) {
            int row = wm * 64 + i * 16 + lr;
            af[i] = __builtin_bit_cast(bf16x8, *(const u16x8*)(&Al[row * 32 + lk * 8]));
        }
        #pragma unroll
        for (int j = 0; j < 4; ++j) {
            int row = wn * 64 + j * 16 + lr;
            bfr[j] = __builtin_bit_cast(bf16x8, *(const u16x8*)(&Bl[row * 32 + lk * 8]));
        }
        #pragma unroll
        for (int i = 0; i < 4; ++i)
            #pragma unroll
            for (int j = 0; j < 4; ++j)
                acc[i][j] = __builtin_amdgcn_mfma_f32_16x16x32_bf16(af[i], bfr[j], acc[i][j], 0, 0, 0);
    }

    int baserow = m0 + wm * 64;
    int basecol = n0 + wn * 64;
    if (EPI == 0) {
        // scatter qkv -> [win][head][n][d] bf16
        #pragma unroll
        for (int i = 0; i < 4; ++i)
            #pragma unroll
            for (int j = 0; j < 4; ++j) {
                int col = basecol + j * 16 + lr;
                int which = col >> 8, rem = col & 255;
                int head = rem >> 5, d = rem & 31;
                u16* dst = (which == 0) ? qp : (which == 1) ? kp : vp;
                float bi = bias[col];
                #pragma unroll
                for (int rg = 0; rg < 4; ++rg) {
                    int row = baserow + i * 16 + lk * 4 + rg;
                    int win = row >> 6, n = row & 63;
                    dst[(((size_t)win * 8 + head) * 64 + n) * 32 + d] = f2bf(acc[i][j][rg] + bi);
                }
            }
    } else {
        // proj epilogue: un-window + un-shift -> y_lin[b][h][w][c] bf16
        #pragma unroll
        for (int i = 0; i < 4; ++i)
            #pragma unroll
            for (int rg = 0; rg < 4; ++rg) {
                int row = baserow + i * 16 + lk * 4 + rg;
                int win = row >> 6, n = row & 63;
                int b = win >> 8, wh = (win >> 4) & 15, ww = win & 15;
                int r = n >> 3, s = n & 7;
                int h = (wh * 8 + r + SHIFT) & 127;
                int w = (ww * 8 + s + SHIFT) & 127;
                size_t base = (((size_t)b * H_ + h) * W_ + w) * C_;
                #pragma unroll
                for (int j = 0; j < 4; ++j) {
                    int col = basecol + j * 16 + lr;
                    yl[base + col] = f2bf(acc[i][j][rg] + bias[col]);
                }
            }
    }
}

// ---------------- K4: windowed attention, 1 wave per (win, head) ----------------
__global__ __launch_bounds__(64) void k_attn(const u16* __restrict__ q,
                                             const u16* __restrict__ kk,
                                             const u16* __restrict__ v,
                                             u16* __restrict__ o) {
    __shared__ __align__(16) u16 P[64 * 72];
    __shared__ __align__(16) u16 Vt[32 * 64];
    int wh = blockIdx.x;                 // win*8 + head
    int lane = threadIdx.x;
    int lr = lane & 15, lk = lane >> 4;
    const u16* qb = q + (size_t)wh * 2048;
    const u16* kb = kk + (size_t)wh * 2048;
    const u16* vb = v + (size_t)wh * 2048;

    // Vt[d][n] = v[n][d]
    #pragma unroll
    for (int dc = 0; dc < 4; ++dc) {
        u16x8 vv = *(const u16x8*)(vb + lane * 32 + dc * 8);
        #pragma unroll
        for (int jj = 0; jj < 8; ++jj) Vt[(dc * 8 + jj) * 64 + lane] = vv[jj];
    }

    const f32x4 fz = {0.f, 0.f, 0.f, 0.f};
    f32x4 sacc[4][4];
    #pragma unroll
    for (int i = 0; i < 4; ++i)
        #pragma unroll
        for (int j = 0; j < 4; ++j) sacc[i][j] = fz;

    bf16x8 qf[4], kf[4];
    #pragma unroll
    for (int i = 0; i < 4; ++i)
        qf[i] = __builtin_bit_cast(bf16x8, *(const u16x8*)(qb + (i * 16 + lr) * 32 + lk * 8));
    #pragma unroll
    for (int j = 0; j < 4; ++j)
        kf[j] = __builtin_bit_cast(bf16x8, *(const u16x8*)(kb + (j * 16 + lr) * 32 + lk * 8));
    #pragma unroll
    for (int i = 0; i < 4; ++i)
        #pragma unroll
        for (int j = 0; j < 4; ++j)
            sacc[i][j] = __builtin_amdgcn_mfma_f32_16x16x32_bf16(qf[i], kf[j], sacc[i][j], 0, 0, 0);

    const float scale = 0.17677669529663687f;   // 32^-0.5
    #pragma unroll
    for (int i = 0; i < 4; ++i) {
        #pragma unroll
        for (int rg = 0; rg < 4; ++rg) {
            float s0 = sacc[i][0][rg] * scale, s1 = sacc[i][1][rg] * scale;
            float s2 = sacc[i][2][rg] * scale, s3 = sacc[i][3][rg] * scale;
            float mx = fmaxf(fmaxf(s0, s1), fmaxf(s2, s3));
            mx = fmaxf(mx, __shfl_xor(mx, 1));
            mx = fmaxf(mx, __shfl_xor(mx, 2));
            mx = fmaxf(mx, __shfl_xor(mx, 4));
            mx = fmaxf(mx, __shfl_xor(mx, 8));
            float p0 = __expf(s0 - mx), p1 = __expf(s1 - mx);
            float p2 = __expf(s2 - mx), p3 = __expf(s3 - mx);
            float sm = p0 + p1 + p2 + p3;
            sm += __shfl_xor(sm, 1);
            sm += __shfl_xor(sm, 2);
            sm += __shfl_xor(sm, 4);
            sm += __shfl_xor(sm, 8);
            float rs = 1.f / sm;
            int row = i * 16 + lk * 4 + rg;
            P[row * 72 + 0 * 16 + lr] = f2bf(p0 * rs);
            P[row * 72 + 1 * 16 + lr] = f2bf(p1 * rs);
            P[row * 72 + 2 * 16 + lr] = f2bf(p2 * rs);
            P[row * 72 + 3 * 16 + lr] = f2bf(p3 * rs);
        }
    }
    __syncthreads();

    f32x4 oacc[4][2];
    #pragma unroll
    for (int i = 0; i < 4; ++i)
        #pragma unroll
        for (int j = 0; j < 2; ++j) oacc[i][j] = fz;
    #pragma unroll
    for (int ks = 0; ks < 2; ++ks) {
        bf16x8 pf[4], vf[2];
        #pragma unroll
        for (int i = 0; i < 4; ++i)
            pf[i] = __builtin_bit_cast(bf16x8, *(const u16x8*)(&P[(i * 16 + lr) * 72 + ks * 32 + lk * 8]));
        #pragma unroll
        for (int j = 0; j < 2; ++j)
            vf[j] = __builtin_bit_cast(bf16x8, *(const u16x8*)(&Vt[(j * 16 + lr) * 64 + ks * 32 + lk * 8]));
        #pragma unroll
        for (int i = 0; i < 4; ++i)
            #pragma unroll
            for (int j = 0; j < 2; ++j)
                oacc[i][j] = __builtin_amdgcn_mfma_f32_16x16x32_bf16(pf[i], vf[j], oacc[i][j], 0, 0, 0);
    }
    int win = wh >> 3, head = wh & 7;
    #pragma unroll
    for (int i = 0; i < 4; ++i)
        #pragma unroll
        for (int j = 0; j < 2; ++j)
            #pragma unroll
            for (int rg = 0; rg < 4; ++rg) {
                int qr = i * 16 + lk * 4 + rg;
                o[((size_t)win * 64 + qr) * 256 + head * 32 + j * 16 + lr] = f2bf(oacc[i][j][rg]);
            }
}

// ---------------- K6: out[b][c][h][w] = 2*(y_lin[b][h][w][c] + x[b][c][h][w]) ----------------
__global__ __launch_bounds__(256) void k_final(const u16* __restrict__ ylin,
                                               const float* __restrict__ x,
                                               float* __restrict__ out) {
    __shared__ float tl[32][33];
    int bx = blockIdx.x;
    int wt = bx >> 3, ct = bx & 7;
    int h = blockIdx.y, b = blockIdx.z;
    int t = threadIdx.x;
    #pragma unroll
    for (int i = 0; i < 4; ++i) {
        int wl = i * 8 + (t >> 5);
        int c = t & 31;
        tl[wl][c] = bf2f(ylin[(((size_t)b * H_ + h) * W_ + wt * 32 + wl) * C_ + ct * 32 + c]);
    }
    __syncthreads();
    #pragma unroll
    for (int i = 0; i < 4; ++i) {
        int cl = i * 8 + (t >> 5);
        int wl = t & 31;
        size_t oi = (((size_t)b * C_ + ct * 32 + cl) * H_ + h) * W_ + wt * 32 + wl;
        out[oi] = 2.f * (tl[wl][cl] + x[oi]);
    }
}

extern "C" void kernel_launch(void* const* d_in, const int* in_sizes, int n_in,
                              void* d_out, int out_size, void* d_ws, size_t ws_size,
                              hipStream_t stream) {
    const float* x     = (const float*)d_in[0];
    const float* g1    = (const float*)d_in[1];
    const float* bb1   = (const float*)d_in[2];
    const float* wqkv  = (const float*)d_in[3];
    const float* bqkv  = (const float*)d_in[4];
    const float* wproj = (const float*)d_in[5];
    const float* bproj = (const float*)d_in[6];
    float* out = (float*)d_out;

    char* ws = (char*)d_ws;
    float* mean  = (float*)ws;                                   // 512 KiB
    float* rstd  = (float*)(ws + (512 << 10));                   // 512 KiB
    u16* wqkvT   = (u16*)(ws + (1 << 20));                       // 384 KiB
    u16* wprojT  = (u16*)(ws + (1 << 20) + (384 << 10));         // 128 KiB
    u16* ywin    = (u16*)(ws + (2ull << 20));                    // 64 MiB
    u16* obuf    = ywin;                                         // alias (ywin dead after gemm<0>)
    u16* vbuf    = (u16*)(ws + (2ull << 20) + (64ull << 20));    // 64 MiB
    u16* ylin    = vbuf;                                         // alias (v dead after attn)
    u16* qbuf    = (u16*)d_out;                                  // d_out as scratch: q 64 MiB
    u16* kbuf    = qbuf + (size_t)NTOK * 256;                    // k 64 MiB

    k_prep_w<<<1024, 256, 0, stream>>>(wqkv, wproj, wqkvT, wprojT);
    k_stats<<<NPIX / 256, 256, 0, stream>>>(x, mean, rstd);
    k_ln_win<<<dim3(4, 128, 8), 256, 0, stream>>>(x, mean, rstd, g1, bb1, ywin);
    k_gemm<0><<<(NTOK / 128) * 6, 256, 0, stream>>>(ywin, wqkvT, bqkv, qbuf, kbuf, vbuf, nullptr, NTOK, 768);
    k_attn<<<NWIN * 8, 64, 0, stream>>>(qbuf, kbuf, vbuf, obuf);
    k_gemm<1><<<(NTOK / 128) * 2, 256, 0, stream>>>(obuf, wprojT, bproj, nullptr, nullptr, nullptr, ylin, NTOK, 256);
    k_final<<<dim3(32, 128, 8), 256, 0, stream>>>(ylin, x, out);
}

// Round 3
// 305.180 us; speedup vs baseline: 1.2451x; 1.0490x over previous
//
#include <hip/hip_runtime.h>
#include <stdint.h>

#define SHIFT 4
#define EPS 1e-5f

#define B_ 8
#define C_ 256
#define H_ 128
#define W_ 128
#define HW_ (H_*W_)
#define NPIX (B_*H_*W_)      // 131072 pixels
#define NWIN 2048            // 8 * 16 * 16 windows
#define NTOK (NWIN*64)       // 131072 token rows

typedef unsigned short u16;
typedef float f32x4 __attribute__((ext_vector_type(4)));
typedef __bf16 bf16x8 __attribute__((ext_vector_type(8)));
typedef unsigned short u16x8 __attribute__((ext_vector_type(8)));
typedef uint32_t u32x4 __attribute__((ext_vector_type(4)));

#define GLOAD16(gp, lp) __builtin_amdgcn_global_load_lds( \
    (const __attribute__((address_space(1))) uint32_t*)(gp), \
    (__attribute__((address_space(3))) uint32_t*)(lp), 16, 0, 0)

static __device__ __forceinline__ u16 f2bf(float f) {
    uint32_t u = __builtin_bit_cast(uint32_t, f);
    u = u + 0x7fffu + ((u >> 16) & 1u);
    return (u16)(u >> 16);
}
static __device__ __forceinline__ float bf2f(u16 u) {
    return __builtin_bit_cast(float, (uint32_t)u << 16);
}

// ---------------- K0: weight transpose+convert ----------------
__global__ void k_prep_w(const float* __restrict__ wqkv, const float* __restrict__ wproj,
                         u16* __restrict__ wqkvT, u16* __restrict__ wprojT) {
    int i = blockIdx.x * blockDim.x + threadIdx.x;
    if (i < 768 * 256) {
        int n = i >> 8, k = i & 255;
        wqkvT[i] = f2bf(wqkv[k * 768 + n]);
    } else {
        int j = i - 768 * 256;   // < 65536
        int n = j >> 8, k = j & 255;
        wprojT[j] = f2bf(wproj[k * 256 + n]);
    }
}

// ---------------- K1: fused LN stats + LN + shift + window partition ----------------
// block = one (b, h_src) row of 128 pixels x 256 channels; grid (128, 8)
__global__ __launch_bounds__(256) void k_ln_win(const float* __restrict__ x,
                                                const float* __restrict__ g,
                                                const float* __restrict__ beta,
                                                u16* __restrict__ ywin) {
    __shared__ u16 sv[256][130];          // bf16 staged row, padded
    __shared__ float ps[2][128];
    __shared__ float pss[2][128];
    __shared__ float mval[128];
    __shared__ float rval[128];
    int h = blockIdx.x;                   // source h
    int b = blockIdx.y;
    int t = threadIdx.x;
    int p = t >> 7, w = t & 127;
    const float* xb = x + (size_t)b * C_ * HW_ + (size_t)h * W_;
    float s = 0.f, ss = 0.f;
    #pragma unroll 8
    for (int it = 0; it < 128; ++it) {
        int c = it * 2 + p;
        float v = xb[(size_t)c * HW_ + w];
        s += v; ss += v * v;
        sv[c][w] = f2bf(v);
    }
    ps[p][w] = s;
    pss[p][w] = ss;
    __syncthreads();
    if (t < 128) {
        float st = ps[0][t] + ps[1][t];
        float sst = pss[0][t] + pss[1][t];
        float m = st * (1.f / C_);
        float var = sst * (1.f / C_) - m * m;
        mval[t] = m;
        rval[t] = rsqrtf(var + EPS);
    }
    __syncthreads();
    // write phase: target row hp = (h - SHIFT) & 127, iterate target wp
    int hp = (h - SHIFT) & 127;
    int wh = hp >> 3, r = hp & 7;
    int c = t;
    float gc = g[c], bc = beta[c];
    int winbase = (b * 16 + wh) * 16;
    #pragma unroll 4
    for (int wp = 0; wp < 128; ++wp) {
        int wsrc = (wp + SHIFT) & 127;
        float v = bf2f(sv[c][wsrc]);
        float yv = (v - mval[wsrc]) * rval[wsrc] * gc + bc;
        int row = (winbase + (wp >> 3)) * 64 + r * 8 + (wp & 7);
        ywin[(size_t)row * C_ + c] = f2bf(yv);
    }
}

// ---------------- GEMM: A[M][256] bf16 @ Bt[N][256] bf16 ----------------
// 128x128 tile, BK=32, 4 waves (2x2), global_load_lds w16 staging,
// 2-phase double-buffered pipeline (STAGE next before compute, one barrier/iter),
// XCD-aware block swizzle for A-panel L2 reuse.
template<int EPI>
__global__ __launch_bounds__(256) void k_gemm(const u16* __restrict__ A,
                                              const u16* __restrict__ Bt,
                                              const float* __restrict__ bias,
                                              u16* __restrict__ qp, u16* __restrict__ kp,
                                              u16* __restrict__ vp, u16* __restrict__ yl,
                                              int M, int N) {
    __shared__ __align__(16) u16 Al[2][128 * 32];
    __shared__ __align__(16) u16 Bl[2][128 * 32];
    int tiles_n = N >> 7;
    int nwg = gridDim.x;
    int bid = blockIdx.x;
    int swz = (bid & 7) * (nwg >> 3) + (bid >> 3);
    int m0 = (swz / tiles_n) << 7;
    int n0 = (swz % tiles_n) << 7;
    int t = threadIdx.x;
    int wave = t >> 6, lane = t & 63;
    int wm = wave >> 1, wn = wave & 1;
    int lr = lane & 15, lk = lane >> 4;
    int srow = (wave << 4) + (lane >> 2);    // row within 64-row half
    int scol = (lane & 3) << 3;              // u16 element offset in row

    const f32x4 fz = {0.f, 0.f, 0.f, 0.f};
    f32x4 acc[4][4];
    #pragma unroll
    for (int i = 0; i < 4; ++i)
        #pragma unroll
        for (int j = 0; j < 4; ++j) acc[i][j] = fz;

    const u16* gA = A + ((size_t)(m0 + srow) << 8) + scol;
    const u16* gB = Bt + ((size_t)(n0 + srow) << 8) + scol;

    #define STAGE(buf, k0) do { \
        char* la_ = (char*)Al[buf] + wave * 1024; \
        char* lb_ = (char*)Bl[buf] + wave * 1024; \
        GLOAD16(gA + (k0), la_); \
        GLOAD16(gA + (k0) + (64 << 8), la_ + 4096); \
        GLOAD16(gB + (k0), lb_); \
        GLOAD16(gB + (k0) + (64 << 8), lb_ + 4096); \
    } while (0)

    STAGE(0, 0);
    __syncthreads();
    int cur = 0;
    #pragma unroll
    for (int kt = 0; kt < 8; ++kt) {
        if (kt < 7) STAGE(cur ^ 1, (kt + 1) * 32);
        bf16x8 af[4], bfr[4];
        #pragma unroll
        for (int i = 0; i < 4; ++i) {
            int row = wm * 64 + i * 16 + lr;
            af[i] = __builtin_bit_cast(bf16x8, *(const u16x8*)(&Al[cur][row * 32 + lk * 8]));
        }
        #pragma unroll
        for (int j = 0; j < 4; ++j) {
            int row = wn * 64 + j * 16 + lr;
            bfr[j] = __builtin_bit_cast(bf16x8, *(const u16x8*)(&Bl[cur][row * 32 + lk * 8]));
        }
        #pragma unroll
        for (int i = 0; i < 4; ++i)
            #pragma unroll
            for (int j = 0; j < 4; ++j)
                acc[i][j] = __builtin_amdgcn_mfma_f32_16x16x32_bf16(af[i], bfr[j], acc[i][j], 0, 0, 0);
        __syncthreads();   // drains STAGE (vmcnt) + ds_reads (lgkm) AFTER compute
        cur ^= 1;
    }
    #undef STAGE

    int baserow = m0 + wm * 64;
    int basecol = n0 + wn * 64;
    if (EPI == 0) {
        // scatter qkv -> [win][head][n][d] bf16
        #pragma unroll
        for (int i = 0; i < 4; ++i)
            #pragma unroll
            for (int j = 0; j < 4; ++j) {
                int col = basecol + j * 16 + lr;
                int which = col >> 8, rem = col & 255;
                int head = rem >> 5, d = rem & 31;
                u16* dst = (which == 0) ? qp : (which == 1) ? kp : vp;
                float bi = bias[col];
                #pragma unroll
                for (int rg = 0; rg < 4; ++rg) {
                    int row = baserow + i * 16 + lk * 4 + rg;
                    int win = row >> 6, n = row & 63;
                    dst[(((size_t)win * 8 + head) * 64 + n) * 32 + d] = f2bf(acc[i][j][rg] + bi);
                }
            }
    } else {
        // proj epilogue: un-window + un-shift -> y_lin[b][h][w][c] bf16
        #pragma unroll
        for (int i = 0; i < 4; ++i)
            #pragma unroll
            for (int rg = 0; rg < 4; ++rg) {
                int row = baserow + i * 16 + lk * 4 + rg;
                int win = row >> 6, n = row & 63;
                int b = win >> 8, wh = (win >> 4) & 15, ww = win & 15;
                int r = n >> 3, s = n & 7;
                int h = (wh * 8 + r + SHIFT) & 127;
                int w = (ww * 8 + s + SHIFT) & 127;
                size_t base = (((size_t)b * H_ + h) * W_ + w) * C_;
                #pragma unroll
                for (int j = 0; j < 4; ++j) {
                    int col = basecol + j * 16 + lr;
                    yl[base + col] = f2bf(acc[i][j][rg] + bias[col]);
                }
            }
    }
}

// ---------------- K4: windowed attention, 1 wave per (win, head) ----------------
__global__ __launch_bounds__(64) void k_attn(const u16* __restrict__ q,
                                             const u16* __restrict__ kk,
                                             const u16* __restrict__ v,
                                             u16* __restrict__ o) {
    __shared__ __align__(16) u16 P[64 * 72];
    __shared__ __align__(16) u16 Vt[32 * 64];
    int wh = blockIdx.x;                 // win*8 + head
    int lane = threadIdx.x;
    int lr = lane & 15, lk = lane >> 4;
    const u16* qb = q + (size_t)wh * 2048;
    const u16* kb = kk + (size_t)wh * 2048;
    const u16* vb = v + (size_t)wh * 2048;

    // Vt[d][n] = v[n][d]
    #pragma unroll
    for (int dc = 0; dc < 4; ++dc) {
        u16x8 vv = *(const u16x8*)(vb + lane * 32 + dc * 8);
        #pragma unroll
        for (int jj = 0; jj < 8; ++jj) Vt[(dc * 8 + jj) * 64 + lane] = vv[jj];
    }

    const f32x4 fz = {0.f, 0.f, 0.f, 0.f};
    f32x4 sacc[4][4];
    #pragma unroll
    for (int i = 0; i < 4; ++i)
        #pragma unroll
        for (int j = 0; j < 4; ++j) sacc[i][j] = fz;

    bf16x8 qf[4], kf[4];
    #pragma unroll
    for (int i = 0; i < 4; ++i)
        qf[i] = __builtin_bit_cast(bf16x8, *(const u16x8*)(qb + (i * 16 + lr) * 32 + lk * 8));
    #pragma unroll
    for (int j = 0; j < 4; ++j)
        kf[j] = __builtin_bit_cast(bf16x8, *(const u16x8*)(kb + (j * 16 + lr) * 32 + lk * 8));
    #pragma unroll
    for (int i = 0; i < 4; ++i)
        #pragma unroll
        for (int j = 0; j < 4; ++j)
            sacc[i][j] = __builtin_amdgcn_mfma_f32_16x16x32_bf16(qf[i], kf[j], sacc[i][j], 0, 0, 0);

    const float scale = 0.17677669529663687f;   // 32^-0.5
    #pragma unroll
    for (int i = 0; i < 4; ++i) {
        #pragma unroll
        for (int rg = 0; rg < 4; ++rg) {
            float s0 = sacc[i][0][rg] * scale, s1 = sacc[i][1][rg] * scale;
            float s2 = sacc[i][2][rg] * scale, s3 = sacc[i][3][rg] * scale;
            float mx = fmaxf(fmaxf(s0, s1), fmaxf(s2, s3));
            mx = fmaxf(mx, __shfl_xor(mx, 1));
            mx = fmaxf(mx, __shfl_xor(mx, 2));
            mx = fmaxf(mx, __shfl_xor(mx, 4));
            mx = fmaxf(mx, __shfl_xor(mx, 8));
            float p0 = __expf(s0 - mx), p1 = __expf(s1 - mx);
            float p2 = __expf(s2 - mx), p3 = __expf(s3 - mx);
            float sm = p0 + p1 + p2 + p3;
            sm += __shfl_xor(sm, 1);
            sm += __shfl_xor(sm, 2);
            sm += __shfl_xor(sm, 4);
            sm += __shfl_xor(sm, 8);
            float rs = 1.f / sm;
            int row = i * 16 + lk * 4 + rg;
            P[row * 72 + 0 * 16 + lr] = f2bf(p0 * rs);
            P[row * 72 + 1 * 16 + lr] = f2bf(p1 * rs);
            P[row * 72 + 2 * 16 + lr] = f2bf(p2 * rs);
            P[row * 72 + 3 * 16 + lr] = f2bf(p3 * rs);
        }
    }
    __syncthreads();

    f32x4 oacc[4][2];
    #pragma unroll
    for (int i = 0; i < 4; ++i)
        #pragma unroll
        for (int j = 0; j < 2; ++j) oacc[i][j] = fz;
    #pragma unroll
    for (int ks = 0; ks < 2; ++ks) {
        bf16x8 pf[4], vf[2];
        #pragma unroll
        for (int i = 0; i < 4; ++i)
            pf[i] = __builtin_bit_cast(bf16x8, *(const u16x8*)(&P[(i * 16 + lr) * 72 + ks * 32 + lk * 8]));
        #pragma unroll
        for (int j = 0; j < 2; ++j)
            vf[j] = __builtin_bit_cast(bf16x8, *(const u16x8*)(&Vt[(j * 16 + lr) * 64 + ks * 32 + lk * 8]));
        #pragma unroll
        for (int i = 0; i < 4; ++i)
            #pragma unroll
            for (int j = 0; j < 2; ++j)
                oacc[i][j] = __builtin_amdgcn_mfma_f32_16x16x32_bf16(pf[i], vf[j], oacc[i][j], 0, 0, 0);
    }
    int win = wh >> 3, head = wh & 7;
    #pragma unroll
    for (int i = 0; i < 4; ++i)
        #pragma unroll
        for (int j = 0; j < 2; ++j)
            #pragma unroll
            for (int rg = 0; rg < 4; ++rg) {
                int qr = i * 16 + lk * 4 + rg;
                o[((size_t)win * 64 + qr) * 256 + head * 32 + j * 16 + lr] = f2bf(oacc[i][j][rg]);
            }
}

// ---------------- K6: out[b][c][h][w] = 2*(y_lin[b][h][w][c] + x[b][c][h][w]) ----------------
__global__ __launch_bounds__(256) void k_final(const u16* __restrict__ ylin,
                                               const float* __restrict__ x,
                                               float* __restrict__ out) {
    __shared__ float tl[32][33];
    int bx = blockIdx.x;
    int wt = bx >> 3, ct = bx & 7;
    int h = blockIdx.y, b = blockIdx.z;
    int t = threadIdx.x;
    #pragma unroll
    for (int i = 0; i < 4; ++i) {
        int wl = i * 8 + (t >> 5);
        int c = t & 31;
        tl[wl][c] = bf2f(ylin[(((size_t)b * H_ + h) * W_ + wt * 32 + wl) * C_ + ct * 32 + c]);
    }
    __syncthreads();
    #pragma unroll
    for (int i = 0; i < 4; ++i) {
        int cl = i * 8 + (t >> 5);
        int wl = t & 31;
        size_t oi = (((size_t)b * C_ + ct * 32 + cl) * H_ + h) * W_ + wt * 32 + wl;
        out[oi] = 2.f * (tl[wl][cl] + x[oi]);
    }
}

extern "C" void kernel_launch(void* const* d_in, const int* in_sizes, int n_in,
                              void* d_out, int out_size, void* d_ws, size_t ws_size,
                              hipStream_t stream) {
    const float* x     = (const float*)d_in[0];
    const float* g1    = (const float*)d_in[1];
    const float* bb1   = (const float*)d_in[2];
    const float* wqkv  = (const float*)d_in[3];
    const float* bqkv  = (const float*)d_in[4];
    const float* wproj = (const float*)d_in[5];
    const float* bproj = (const float*)d_in[6];
    float* out = (float*)d_out;

    char* ws = (char*)d_ws;
    u16* wqkvT   = (u16*)(ws + (1 << 20));                       // 384 KiB
    u16* wprojT  = (u16*)(ws + (1 << 20) + (384 << 10));         // 128 KiB
    u16* ywin    = (u16*)(ws + (2ull << 20));                    // 64 MiB
    u16* obuf    = ywin;                                         // alias (ywin dead after gemm<0>)
    u16* vbuf    = (u16*)(ws + (2ull << 20) + (64ull << 20));    // 64 MiB
    u16* ylin    = vbuf;                                         // alias (v dead after attn)
    u16* qbuf    = (u16*)d_out;                                  // d_out as scratch: q 64 MiB
    u16* kbuf    = qbuf + (size_t)NTOK * 256;                    // k 64 MiB

    k_prep_w<<<1024, 256, 0, stream>>>(wqkv, wproj, wqkvT, wprojT);
    k_ln_win<<<dim3(128, 8), 256, 0, stream>>>(x, g1, bb1, ywin);
    k_gemm<0><<<(NTOK / 128) * 6, 256, 0, stream>>>(ywin, wqkvT, bqkv, qbuf, kbuf, vbuf, nullptr, NTOK, 768);
    k_attn<<<NWIN * 8, 64, 0, stream>>>(qbuf, kbuf, vbuf, obuf);
    k_gemm<1><<<(NTOK / 128) * 2, 256, 0, stream>>>(obuf, wprojT, bproj, nullptr, nullptr, nullptr, ylin, NTOK, 256);
    k_final<<<dim3(32, 128, 8), 256, 0, stream>>>(ylin, x, out);
}

// Round 4
// 300.240 us; speedup vs baseline: 1.2656x; 1.0165x over previous
//
#include <hip/hip_runtime.h>
#include <stdint.h>

#define SHIFT 4
#define EPS 1e-5f

#define B_ 8
#define C_ 256
#define H_ 128
#define W_ 128
#define HW_ (H_*W_)
#define NPIX (B_*H_*W_)      // 131072 pixels
#define NWIN 2048            // 8 * 16 * 16 windows
#define NTOK (NWIN*64)       // 131072 token rows

typedef unsigned short u16;
typedef float f32x4 __attribute__((ext_vector_type(4)));
typedef __bf16 bf16x8 __attribute__((ext_vector_type(8)));
typedef unsigned short u16x8 __attribute__((ext_vector_type(8)));
typedef uint32_t u32x4 __attribute__((ext_vector_type(4)));

#define GLOAD16(gp, lp) __builtin_amdgcn_global_load_lds( \
    (const __attribute__((address_space(1))) uint32_t*)(gp), \
    (__attribute__((address_space(3))) uint32_t*)(lp), 16, 0, 0)

static __device__ __forceinline__ u16 f2bf(float f) {
    uint32_t u = __builtin_bit_cast(uint32_t, f);
    u = u + 0x7fffu + ((u >> 16) & 1u);
    return (u16)(u >> 16);
}
static __device__ __forceinline__ float bf2f(u16 u) {
    return __builtin_bit_cast(float, (uint32_t)u << 16);
}

// ---------------- K0: weight transpose+convert ----------------
__global__ void k_prep_w(const float* __restrict__ wqkv, const float* __restrict__ wproj,
                         u16* __restrict__ wqkvT, u16* __restrict__ wprojT) {
    int i = blockIdx.x * blockDim.x + threadIdx.x;
    if (i < 768 * 256) {
        int n = i >> 8, k = i & 255;
        wqkvT[i] = f2bf(wqkv[k * 768 + n]);
    } else {
        int j = i - 768 * 256;   // < 65536
        int n = j >> 8, k = j & 255;
        wprojT[j] = f2bf(wproj[k * 256 + n]);
    }
}

// ---------------- K1: fused LN stats + LN + shift + window partition ----------------
__global__ __launch_bounds__(256) void k_ln_win(const float* __restrict__ x,
                                                const float* __restrict__ g,
                                                const float* __restrict__ beta,
                                                u16* __restrict__ ywin) {
    __shared__ u16 sv[256][130];          // bf16 staged row, padded
    __shared__ float ps[2][128];
    __shared__ float pss[2][128];
    __shared__ float mval[128];
    __shared__ float rval[128];
    int h = blockIdx.x;                   // source h
    int b = blockIdx.y;
    int t = threadIdx.x;
    int p = t >> 7, w = t & 127;
    const float* xb = x + (size_t)b * C_ * HW_ + (size_t)h * W_;
    float s = 0.f, ss = 0.f;
    #pragma unroll 8
    for (int it = 0; it < 128; ++it) {
        int c = it * 2 + p;
        float v = xb[(size_t)c * HW_ + w];
        s += v; ss += v * v;
        sv[c][w] = f2bf(v);
    }
    ps[p][w] = s;
    pss[p][w] = ss;
    __syncthreads();
    if (t < 128) {
        float st = ps[0][t] + ps[1][t];
        float sst = pss[0][t] + pss[1][t];
        float m = st * (1.f / C_);
        float var = sst * (1.f / C_) - m * m;
        mval[t] = m;
        rval[t] = rsqrtf(var + EPS);
    }
    __syncthreads();
    int hp = (h - SHIFT) & 127;
    int wh = hp >> 3, r = hp & 7;
    int c = t;
    float gc = g[c], bc = beta[c];
    int winbase = (b * 16 + wh) * 16;
    #pragma unroll 4
    for (int wp = 0; wp < 128; ++wp) {
        int wsrc = (wp + SHIFT) & 127;
        float v = bf2f(sv[c][wsrc]);
        float yv = (v - mval[wsrc]) * rval[wsrc] * gc + bc;
        int row = (winbase + (wp >> 3)) * 64 + r * 8 + (wp & 7);
        ywin[(size_t)row * C_ + c] = f2bf(yv);
    }
}

// ---------------- GEMM: A[M][256] bf16 @ Bt[N][256] bf16 ----------------
// 128x128 tile, BK=32, 4 waves (2x2). 3-deep counted-vmcnt pipeline with
// global_load_lds w16 staging; bank-conflict-free via pre-swizzled source
// (linear LDS dest, chunk XOR on read). XCD-aware block swizzle.
template<int EPI>
__global__ __launch_bounds__(256) void k_gemm(const u16* __restrict__ A,
                                              const u16* __restrict__ Bt,
                                              const float* __restrict__ bias,
                                              u16* __restrict__ qp, u16* __restrict__ kp,
                                              u16* __restrict__ vp, u16* __restrict__ yl,
                                              int M, int N) {
    __shared__ __align__(16) u16 Al[3][128 * 32];
    __shared__ __align__(16) u16 Bl[3][128 * 32];
    int tiles_n = N >> 7;
    int nwg = gridDim.x;
    int bid = blockIdx.x;
    int swz = (bid & 7) * (nwg >> 3) + (bid >> 3);
    int m0 = (swz / tiles_n) << 7;
    int n0 = (swz % tiles_n) << 7;
    int t = threadIdx.x;
    int wave = t >> 6, lane = t & 63;
    int wm = wave >> 1, wn = wave & 1;
    int lr = lane & 15, lk = lane >> 4;
    // staging: lane covers physical slot (row = wave*16 + lane/4, chunk = lane&3).
    // source chunk = phys_chunk ^ s(row), s(row) = (row>>1)&3 = (lane>>3)&3
    int srow = (wave << 4) + (lane >> 2);
    int scol = (((lane & 3) ^ ((lane >> 3) & 3)) << 3);   // u16 offset
    // fragment read chunk xor: s = (lr>>1)&3
    int sx = (lr >> 1) & 3;
    int ka = ((lk ^ sx) << 3);                             // u16 offset of k-chunk

    const f32x4 fz = {0.f, 0.f, 0.f, 0.f};
    f32x4 acc[4][4];
    #pragma unroll
    for (int i = 0; i < 4; ++i)
        #pragma unroll
        for (int j = 0; j < 4; ++j) acc[i][j] = fz;

    const u16* gA = A + ((size_t)(m0 + srow) << 8) + scol;
    const u16* gB = Bt + ((size_t)(n0 + srow) << 8) + scol;

    #define STAGE(buf, ks) do { \
        char* la_ = (char*)Al[buf] + wave * 1024; \
        char* lb_ = (char*)Bl[buf] + wave * 1024; \
        GLOAD16(gA + (ks) * 32, la_); \
        GLOAD16(gA + (ks) * 32 + (64 << 8), la_ + 4096); \
        GLOAD16(gB + (ks) * 32, lb_); \
        GLOAD16(gB + (ks) * 32 + (64 << 8), lb_ + 4096); \
    } while (0)

    STAGE(0, 0);
    STAGE(1, 1);
    STAGE(2, 2);
    #pragma unroll
    for (int kt = 0; kt < 8; ++kt) {
        const int b = kt % 3;
        // wait for stage kt (leave later stages in flight), then barrier.
        // fused in one asm so compiler can't place ds_reads between them.
        if (kt < 6)      asm volatile("s_waitcnt vmcnt(8)\ns_barrier" ::: "memory");
        else if (kt == 6) asm volatile("s_waitcnt vmcnt(4)\ns_barrier" ::: "memory");
        else             asm volatile("s_waitcnt vmcnt(0)\ns_barrier" ::: "memory");
        bf16x8 af[4], bfr[4];
        #pragma unroll
        for (int i = 0; i < 4; ++i) {
            int row = wm * 64 + i * 16 + lr;
            af[i] = __builtin_bit_cast(bf16x8, *(const u16x8*)(&Al[b][row * 32 + ka]));
        }
        #pragma unroll
        for (int j = 0; j < 4; ++j) {
            int row = wn * 64 + j * 16 + lr;
            bfr[j] = __builtin_bit_cast(bf16x8, *(const u16x8*)(&Bl[b][row * 32 + ka]));
        }
        __builtin_amdgcn_s_setprio(1);
        #pragma unroll
        for (int i = 0; i < 4; ++i)
            #pragma unroll
            for (int j = 0; j < 4; ++j)
                acc[i][j] = __builtin_amdgcn_mfma_f32_16x16x32_bf16(af[i], bfr[j], acc[i][j], 0, 0, 0);
        __builtin_amdgcn_s_setprio(0);
        // drain this wave's LDS reads, then barrier; buffer b is then free to restage
        asm volatile("s_waitcnt lgkmcnt(0)\ns_barrier" ::: "memory");
        if (kt < 5) STAGE(b, kt + 3);
    }
    #undef STAGE

    int baserow = m0 + wm * 64;
    int basecol = n0 + wn * 64;
    if (EPI == 0) {
        // scatter qkv -> [win][head][n][d] bf16
        #pragma unroll
        for (int i = 0; i < 4; ++i)
            #pragma unroll
            for (int j = 0; j < 4; ++j) {
                int col = basecol + j * 16 + lr;
                int which = col >> 8, rem = col & 255;
                int head = rem >> 5, d = rem & 31;
                u16* dst = (which == 0) ? qp : (which == 1) ? kp : vp;
                float bi = bias[col];
                #pragma unroll
                for (int rg = 0; rg < 4; ++rg) {
                    int row = baserow + i * 16 + lk * 4 + rg;
                    int win = row >> 6, n = row & 63;
                    dst[(((size_t)win * 8 + head) * 64 + n) * 32 + d] = f2bf(acc[i][j][rg] + bi);
                }
            }
    } else {
        // proj epilogue: un-window + un-shift -> y_lin[b][h][w][c] bf16
        #pragma unroll
        for (int i = 0; i < 4; ++i)
            #pragma unroll
            for (int rg = 0; rg < 4; ++rg) {
                int row = baserow + i * 16 + lk * 4 + rg;
                int win = row >> 6, n = row & 63;
                int b = win >> 8, wh = (win >> 4) & 15, ww = win & 15;
                int r = n >> 3, s = n & 7;
                int h = (wh * 8 + r + SHIFT) & 127;
                int w = (ww * 8 + s + SHIFT) & 127;
                size_t base = (((size_t)b * H_ + h) * W_ + w) * C_;
                #pragma unroll
                for (int j = 0; j < 4; ++j) {
                    int col = basecol + j * 16 + lr;
                    yl[base + col] = f2bf(acc[i][j][rg] + bias[col]);
                }
            }
    }
}

// ---------------- K4: windowed attention, 1 wave per (win, head) ----------------
__global__ __launch_bounds__(64) void k_attn(const u16* __restrict__ q,
                                             const u16* __restrict__ kk,
                                             const u16* __restrict__ v,
                                             u16* __restrict__ o) {
    __shared__ __align__(16) u16 P[64 * 72];
    __shared__ __align__(16) u16 Vt[32 * 64];
    int wh = blockIdx.x;                 // win*8 + head
    int lane = threadIdx.x;
    int lr = lane & 15, lk = lane >> 4;
    const u16* qb = q + (size_t)wh * 2048;
    const u16* kb = kk + (size_t)wh * 2048;
    const u16* vb = v + (size_t)wh * 2048;

    // Vt[d][n] = v[n][d]
    #pragma unroll
    for (int dc = 0; dc < 4; ++dc) {
        u16x8 vv = *(const u16x8*)(vb + lane * 32 + dc * 8);
        #pragma unroll
        for (int jj = 0; jj < 8; ++jj) Vt[(dc * 8 + jj) * 64 + lane] = vv[jj];
    }

    const f32x4 fz = {0.f, 0.f, 0.f, 0.f};
    f32x4 sacc[4][4];
    #pragma unroll
    for (int i = 0; i < 4; ++i)
        #pragma unroll
        for (int j = 0; j < 4; ++j) sacc[i][j] = fz;

    bf16x8 qf[4], kf[4];
    #pragma unroll
    for (int i = 0; i < 4; ++i)
        qf[i] = __builtin_bit_cast(bf16x8, *(const u16x8*)(qb + (i * 16 + lr) * 32 + lk * 8));
    #pragma unroll
    for (int j = 0; j < 4; ++j)
        kf[j] = __builtin_bit_cast(bf16x8, *(const u16x8*)(kb + (j * 16 + lr) * 32 + lk * 8));
    #pragma unroll
    for (int i = 0; i < 4; ++i)
        #pragma unroll
        for (int j = 0; j < 4; ++j)
            sacc[i][j] = __builtin_amdgcn_mfma_f32_16x16x32_bf16(qf[i], kf[j], sacc[i][j], 0, 0, 0);

    const float scale = 0.17677669529663687f;   // 32^-0.5
    #pragma unroll
    for (int i = 0; i < 4; ++i) {
        #pragma unroll
        for (int rg = 0; rg < 4; ++rg) {
            float s0 = sacc[i][0][rg] * scale, s1 = sacc[i][1][rg] * scale;
            float s2 = sacc[i][2][rg] * scale, s3 = sacc[i][3][rg] * scale;
            float mx = fmaxf(fmaxf(s0, s1), fmaxf(s2, s3));
            mx = fmaxf(mx, __shfl_xor(mx, 1));
            mx = fmaxf(mx, __shfl_xor(mx, 2));
            mx = fmaxf(mx, __shfl_xor(mx, 4));
            mx = fmaxf(mx, __shfl_xor(mx, 8));
            float p0 = __expf(s0 - mx), p1 = __expf(s1 - mx);
            float p2 = __expf(s2 - mx), p3 = __expf(s3 - mx);
            float sm = p0 + p1 + p2 + p3;
            sm += __shfl_xor(sm, 1);
            sm += __shfl_xor(sm, 2);
            sm += __shfl_xor(sm, 4);
            sm += __shfl_xor(sm, 8);
            float rs = 1.f / sm;
            int row = i * 16 + lk * 4 + rg;
            P[row * 72 + 0 * 16 + lr] = f2bf(p0 * rs);
            P[row * 72 + 1 * 16 + lr] = f2bf(p1 * rs);
            P[row * 72 + 2 * 16 + lr] = f2bf(p2 * rs);
            P[row * 72 + 3 * 16 + lr] = f2bf(p3 * rs);
        }
    }
    __syncthreads();

    f32x4 oacc[4][2];
    #pragma unroll
    for (int i = 0; i < 4; ++i)
        #pragma unroll
        for (int j = 0; j < 2; ++j) oacc[i][j] = fz;
    #pragma unroll
    for (int ks = 0; ks < 2; ++ks) {
        bf16x8 pf[4], vf[2];
        #pragma unroll
        for (int i = 0; i < 4; ++i)
            pf[i] = __builtin_bit_cast(bf16x8, *(const u16x8*)(&P[(i * 16 + lr) * 72 + ks * 32 + lk * 8]));
        #pragma unroll
        for (int j = 0; j < 2; ++j)
            vf[j] = __builtin_bit_cast(bf16x8, *(const u16x8*)(&Vt[(j * 16 + lr) * 64 + ks * 32 + lk * 8]));
        #pragma unroll
        for (int i = 0; i < 4; ++i)
            #pragma unroll
            for (int j = 0; j < 2; ++j)
                oacc[i][j] = __builtin_amdgcn_mfma_f32_16x16x32_bf16(pf[i], vf[j], oacc[i][j], 0, 0, 0);
    }
    int win = wh >> 3, head = wh & 7;
    #pragma unroll
    for (int i = 0; i < 4; ++i)
        #pragma unroll
        for (int j = 0; j < 2; ++j)
            #pragma unroll
            for (int rg = 0; rg < 4; ++rg) {
                int qr = i * 16 + lk * 4 + rg;
                o[((size_t)win * 64 + qr) * 256 + head * 32 + j * 16 + lr] = f2bf(oacc[i][j][rg]);
            }
}

// ---------------- K6: out[b][c][h][w] = 2*(y_lin[b][h][w][c] + x[b][c][h][w]) ----------------
__global__ __launch_bounds__(256) void k_final(const u16* __restrict__ ylin,
                                               const float* __restrict__ x,
                                               float* __restrict__ out) {
    __shared__ float tl[32][33];
    int bx = blockIdx.x;
    int wt = bx >> 3, ct = bx & 7;
    int h = blockIdx.y, b = blockIdx.z;
    int t = threadIdx.x;
    #pragma unroll
    for (int i = 0; i < 4; ++i) {
        int wl = i * 8 + (t >> 5);
        int c = t & 31;
        tl[wl][c] = bf2f(ylin[(((size_t)b * H_ + h) * W_ + wt * 32 + wl) * C_ + ct * 32 + c]);
    }
    __syncthreads();
    #pragma unroll
    for (int i = 0; i < 4; ++i) {
        int cl = i * 8 + (t >> 5);
        int wl = t & 31;
        size_t oi = (((size_t)b * C_ + ct * 32 + cl) * H_ + h) * W_ + wt * 32 + wl;
        out[oi] = 2.f * (tl[wl][cl] + x[oi]);
    }
}

extern "C" void kernel_launch(void* const* d_in, const int* in_sizes, int n_in,
                              void* d_out, int out_size, void* d_ws, size_t ws_size,
                              hipStream_t stream) {
    const float* x     = (const float*)d_in[0];
    const float* g1    = (const float*)d_in[1];
    const float* bb1   = (const float*)d_in[2];
    const float* wqkv  = (const float*)d_in[3];
    const float* bqkv  = (const float*)d_in[4];
    const float* wproj = (const float*)d_in[5];
    const float* bproj = (const float*)d_in[6];
    float* out = (float*)d_out;

    char* ws = (char*)d_ws;
    u16* wqkvT   = (u16*)(ws + (1 << 20));                       // 384 KiB
    u16* wprojT  = (u16*)(ws + (1 << 20) + (384 << 10));         // 128 KiB
    u16* ywin    = (u16*)(ws + (2ull << 20));                    // 64 MiB
    u16* obuf    = ywin;                                         // alias (ywin dead after gemm<0>)
    u16* vbuf    = (u16*)(ws + (2ull << 20) + (64ull << 20));    // 64 MiB
    u16* ylin    = vbuf;                                         // alias (v dead after attn)
    u16* qbuf    = (u16*)d_out;                                  // d_out as scratch: q 64 MiB
    u16* kbuf    = qbuf + (size_t)NTOK * 256;                    // k 64 MiB

    k_prep_w<<<1024, 256, 0, stream>>>(wqkv, wproj, wqkvT, wprojT);
    k_ln_win<<<dim3(128, 8), 256, 0, stream>>>(x, g1, bb1, ywin);
    k_gemm<0><<<(NTOK / 128) * 6, 256, 0, stream>>>(ywin, wqkvT, bqkv, qbuf, kbuf, vbuf, nullptr, NTOK, 768);
    k_attn<<<NWIN * 8, 64, 0, stream>>>(qbuf, kbuf, vbuf, obuf);
    k_gemm<1><<<(NTOK / 128) * 2, 256, 0, stream>>>(obuf, wprojT, bproj, nullptr, nullptr, nullptr, ylin, NTOK, 256);
    k_final<<<dim3(32, 128, 8), 256, 0, stream>>>(ylin, x, out);
}

// Round 5
// 260.865 us; speedup vs baseline: 1.4566x; 1.1509x over previous
//
#include <hip/hip_runtime.h>
#include <stdint.h>

#define SHIFT 4
#define EPS 1e-5f

#define B_ 8
#define C_ 256
#define H_ 128
#define W_ 128
#define HW_ (H_*W_)
#define NWIN 2048            // 8 * 16 * 16 windows
#define NTOK (NWIN*64)

typedef unsigned short u16;
typedef float f32x4 __attribute__((ext_vector_type(4)));
typedef __bf16 bf16x8 __attribute__((ext_vector_type(8)));
typedef unsigned short u16x8 __attribute__((ext_vector_type(8)));

#define GLOAD16(gp, lp) __builtin_amdgcn_global_load_lds( \
    (const __attribute__((address_space(1))) uint32_t*)(gp), \
    (__attribute__((address_space(3))) uint32_t*)(lp), 16, 0, 0)

static __device__ __forceinline__ u16 f2bf(float f) {
    uint32_t u = __builtin_bit_cast(uint32_t, f);
    u = u + 0x7fffu + ((u >> 16) & 1u);
    return (u16)(u >> 16);
}
static __device__ __forceinline__ float bf2f(u16 u) {
    return __builtin_bit_cast(float, (uint32_t)u << 16);
}

// ---------------- K0: weight prep into per-fragment streaming order ----------------
// W2q: qkv B-frags: [jg(48)][kt(8)][lane(64)][e(8)]  <- wqkv[k][col], col=jg*16+(l&15), k=kt*32+(l>>4)*8+e
// W2pA: proj A-frags (operand-swapped): [ig(16)][kt(8)][lane(64)][e(8)] <- wproj[k][c], c=ig*16+(l&15)
__global__ __launch_bounds__(256) void k_prep_w(const float* __restrict__ wqkv,
                                                const float* __restrict__ wproj,
                                                u16* __restrict__ W2q, u16* __restrict__ W2pA) {
    int i = blockIdx.x * 256 + threadIdx.x;   // 0 .. 262143
    if (i < 48 * 8 * 64 * 8) {
        int e = i & 7, l = (i >> 3) & 63, kt = (i >> 9) & 7, jg = i >> 12;
        int col = jg * 16 + (l & 15);
        int k = kt * 32 + (l >> 4) * 8 + e;
        W2q[i] = f2bf(wqkv[k * 768 + col]);
    } else {
        int j = i - 48 * 8 * 64 * 8;          // < 65536
        int e = j & 7, l = (j >> 3) & 63, kt = (j >> 9) & 7, ig = j >> 12;
        int c = ig * 16 + (l & 15);
        int k = kt * 32 + (l >> 4) * 8 + e;
        W2pA[j] = f2bf(wproj[k * 256 + c]);
    }
}

// ---------------- K1: fused LN stats + LN + shift + window partition (proven) ----------------
__global__ __launch_bounds__(256) void k_ln_win(const float* __restrict__ x,
                                                const float* __restrict__ g,
                                                const float* __restrict__ beta,
                                                u16* __restrict__ ywin) {
    __shared__ u16 sv[256][130];
    __shared__ float ps[2][128];
    __shared__ float pss[2][128];
    __shared__ float mval[128];
    __shared__ float rval[128];
    int h = blockIdx.x;
    int b = blockIdx.y;
    int t = threadIdx.x;
    int p = t >> 7, w = t & 127;
    const float* xb = x + (size_t)b * C_ * HW_ + (size_t)h * W_;
    float s = 0.f, ss = 0.f;
    #pragma unroll 8
    for (int it = 0; it < 128; ++it) {
        int c = it * 2 + p;
        float v = xb[(size_t)c * HW_ + w];
        s += v; ss += v * v;
        sv[c][w] = f2bf(v);
    }
    ps[p][w] = s;
    pss[p][w] = ss;
    __syncthreads();
    if (t < 128) {
        float st = ps[0][t] + ps[1][t];
        float sst = pss[0][t] + pss[1][t];
        float m = st * (1.f / C_);
        float var = sst * (1.f / C_) - m * m;
        mval[t] = m;
        rval[t] = rsqrtf(var + EPS);
    }
    __syncthreads();
    int hp = (h - SHIFT) & 127;
    int wh = hp >> 3, r = hp & 7;
    int c = t;
    float gc = g[c], bc = beta[c];
    int winbase = (b * 16 + wh) * 16;
    #pragma unroll 4
    for (int wp = 0; wp < 128; ++wp) {
        int wsrc = (wp + SHIFT) & 127;
        float v = bf2f(sv[c][wsrc]);
        float yv = (v - mval[wsrc]) * rval[wsrc] * gc + bc;
        int row = (winbase + (wp >> 3)) * 64 + r * 8 + (wp & 7);
        ywin[(size_t)row * C_ + c] = f2bf(yv);
    }
}

// ---------------- K2: MEGA: qkv GEMM + attention + proj + residual/out ----------------
// 1 block = 1 window (64 tokens), 512 threads = 8 waves (wave w = head w for attn).
// LDS map (bytes):
//   Y  @0      : [64 n][256 c] u16, chunk-XOR: phys16Bchunk = (c>>3)^(n&31)      (32768)
//   QK @32768  : [2][8 head][64 n][40 u16] (d=0..31, row stride 80B)             (81920)
//   VT @114688 : [8 head][32 d][72 u16] (key dim padded, stride 144B)            (36864)
//   P  overlay @ wave*9216 on Y+QK (after S): [64 q][72 u16]                     (73728)
//   O  overlay @114688 on VT (after all PV): [64 token][280 u16] (c dim)         (35840)
// total 151552
__global__ __launch_bounds__(512) void k_fused(const u16* __restrict__ ywin,
                                               const u16* __restrict__ W2q,
                                               const u16* __restrict__ W2pA,
                                               const float* __restrict__ bqkv,
                                               const float* __restrict__ bproj,
                                               const float* __restrict__ x,
                                               float* __restrict__ out) {
    extern __shared__ __align__(16) char smem[];
    u16* Y  = (u16*)smem;
    u16* QK = (u16*)(smem + 32768);
    u16* VT = (u16*)(smem + 114688);
    u16* O  = (u16*)(smem + 114688);

    int bid = blockIdx.x;
    int win = (bid & 7) * 256 + (bid >> 3);      // XCD-chunked: contiguous windows per XCD
    int b = win >> 8, wh = (win >> 4) & 15, ww = win & 15;

    int t = threadIdx.x;
    int wave = t >> 6, lane = t & 63;
    int lr = lane & 15, lk = lane >> 4;

    // ---- P0: stage y window (64 x 256 bf16) with XOR-source pre-swizzle ----
    {
        const u16* base = ywin + (size_t)win * 64 * 256;
        #pragma unroll
        for (int q = 0; q < 4; ++q) {
            int g = wave * 256 + q * 64 + lane;   // granule (16B)
            int n = g >> 5, pc = g & 31;
            int sc = pc ^ (n & 31);
            GLOAD16(base + n * 256 + sc * 8, smem + wave * 4096 + q * 1024);
        }
    }
    __syncthreads();

    // ---- P1: qkv GEMM: 64 x 768, K=256. wave w: cols w*96..w*96+95 ----
    {
        f32x4 acc[4][6];
        #pragma unroll
        for (int i = 0; i < 4; ++i)
            #pragma unroll
            for (int j = 0; j < 6; ++j) acc[i][j] = (f32x4){0.f,0.f,0.f,0.f};
        #pragma unroll
        for (int kt = 0; kt < 8; ++kt) {
            bf16x8 af[4], bf[6];
            #pragma unroll
            for (int i = 0; i < 4; ++i) {
                int n = i * 16 + lr;
                int pc = (kt * 4 + lk) ^ (n & 31);
                af[i] = __builtin_bit_cast(bf16x8, *(const u16x8*)(&Y[n * 256 + pc * 8]));
            }
            #pragma unroll
            for (int j = 0; j < 6; ++j) {
                int jg = wave * 6 + j;
                bf[j] = __builtin_bit_cast(bf16x8,
                    *(const u16x8*)(W2q + (((size_t)(jg * 8 + kt)) << 9) + (lane << 3)));
            }
            #pragma unroll
            for (int i = 0; i < 4; ++i)
                #pragma unroll
                for (int j = 0; j < 6; ++j)
                    acc[i][j] = __builtin_amdgcn_mfma_f32_16x16x32_bf16(af[i], bf[j], acc[i][j], 0, 0, 0);
        }
        // epilogue: scatter into QK (pad-80) / VT (transposed, pad-144)
        #pragma unroll
        for (int j = 0; j < 6; ++j) {
            int col = wave * 96 + j * 16 + lr;
            int which = col >> 8, rem = col & 255;
            int head = rem >> 5, d = rem & 31;
            float bi = bqkv[col];
            #pragma unroll
            for (int i = 0; i < 4; ++i)
                #pragma unroll
                for (int rg = 0; rg < 4; ++rg) {
                    int n = i * 16 + lk * 4 + rg;
                    u16 v = f2bf(acc[i][j][rg] + bi);
                    if (which < 2) QK[which * 20480 + head * 2560 + n * 40 + d] = v;
                    else           VT[head * 2304 + d * 72 + n] = v;
                }
        }
    }
    __syncthreads();

    // ---- P2: attention, wave = head ----
    f32x4 oacc[4][2];
    {
        const u16* qb = QK + wave * 2560;
        const u16* kb = QK + 20480 + wave * 2560;
        f32x4 sacc[4][4];
        #pragma unroll
        for (int i = 0; i < 4; ++i)
            #pragma unroll
            for (int j = 0; j < 4; ++j) sacc[i][j] = (f32x4){0.f,0.f,0.f,0.f};
        bf16x8 qf[4], kf[4];
        #pragma unroll
        for (int i = 0; i < 4; ++i)
            qf[i] = __builtin_bit_cast(bf16x8, *(const u16x8*)(qb + (i * 16 + lr) * 40 + lk * 8));
        #pragma unroll
        for (int j = 0; j < 4; ++j)
            kf[j] = __builtin_bit_cast(bf16x8, *(const u16x8*)(kb + (j * 16 + lr) * 40 + lk * 8));
        #pragma unroll
        for (int i = 0; i < 4; ++i)
            #pragma unroll
            for (int j = 0; j < 4; ++j)
                sacc[i][j] = __builtin_amdgcn_mfma_f32_16x16x32_bf16(qf[i], kf[j], sacc[i][j], 0, 0, 0);
        __syncthreads();   // all S done -> q,k regions now reusable as P

        u16* Pw = (u16*)(smem + wave * 9216);   // [64][72]
        const float scale = 0.17677669529663687f;
        #pragma unroll
        for (int i = 0; i < 4; ++i) {
            #pragma unroll
            for (int rg = 0; rg < 4; ++rg) {
                float s0 = sacc[i][0][rg] * scale, s1 = sacc[i][1][rg] * scale;
                float s2 = sacc[i][2][rg] * scale, s3 = sacc[i][3][rg] * scale;
                float mx = fmaxf(fmaxf(s0, s1), fmaxf(s2, s3));
                mx = fmaxf(mx, __shfl_xor(mx, 1));
                mx = fmaxf(mx, __shfl_xor(mx, 2));
                mx = fmaxf(mx, __shfl_xor(mx, 4));
                mx = fmaxf(mx, __shfl_xor(mx, 8));
                float p0 = __expf(s0 - mx), p1 = __expf(s1 - mx);
                float p2 = __expf(s2 - mx), p3 = __expf(s3 - mx);
                float sm = p0 + p1 + p2 + p3;
                sm += __shfl_xor(sm, 1);
                sm += __shfl_xor(sm, 2);
                sm += __shfl_xor(sm, 4);
                sm += __shfl_xor(sm, 8);
                float rs = 1.f / sm;
                int row = i * 16 + lk * 4 + rg;
                Pw[row * 72 + 0 * 16 + lr] = f2bf(p0 * rs);
                Pw[row * 72 + 1 * 16 + lr] = f2bf(p1 * rs);
                Pw[row * 72 + 2 * 16 + lr] = f2bf(p2 * rs);
                Pw[row * 72 + 3 * 16 + lr] = f2bf(p3 * rs);
            }
        }
        #pragma unroll
        for (int i = 0; i < 4; ++i)
            #pragma unroll
            for (int j = 0; j < 2; ++j) oacc[i][j] = (f32x4){0.f,0.f,0.f,0.f};
        const u16* vtw = VT + wave * 2304;
        #pragma unroll
        for (int ks = 0; ks < 2; ++ks) {
            bf16x8 pf[4], vf[2];
            #pragma unroll
            for (int i = 0; i < 4; ++i)
                pf[i] = __builtin_bit_cast(bf16x8, *(const u16x8*)(&Pw[(i * 16 + lr) * 72 + ks * 32 + lk * 8]));
            #pragma unroll
            for (int j = 0; j < 2; ++j)
                vf[j] = __builtin_bit_cast(bf16x8, *(const u16x8*)(vtw + (j * 16 + lr) * 72 + ks * 32 + lk * 8));
            #pragma unroll
            for (int i = 0; i < 4; ++i)
                #pragma unroll
                for (int j = 0; j < 2; ++j)
                    oacc[i][j] = __builtin_amdgcn_mfma_f32_16x16x32_bf16(pf[i], vf[j], oacc[i][j], 0, 0, 0);
        }
    }
    __syncthreads();   // all PV done -> VT region reusable as O

    // write O[token][c], c = head*32 + d
    #pragma unroll
    for (int i = 0; i < 4; ++i)
        #pragma unroll
        for (int j = 0; j < 2; ++j)
            #pragma unroll
            for (int rg = 0; rg < 4; ++rg) {
                int n = i * 16 + lk * 4 + rg;
                O[n * 280 + wave * 32 + j * 16 + lr] = f2bf(oacc[i][j][rg]);
            }
    __syncthreads();

    // ---- P3: proj (operand-swapped): C[c][token] = sum_k wproj[k][c] * O[token][k] ----
    f32x4 acc2[2][4];
    #pragma unroll
    for (int i = 0; i < 2; ++i)
        #pragma unroll
        for (int j = 0; j < 4; ++j) acc2[i][j] = (f32x4){0.f,0.f,0.f,0.f};
    #pragma unroll
    for (int kt = 0; kt < 8; ++kt) {
        bf16x8 af[2], bo[4];
        #pragma unroll
        for (int i = 0; i < 2; ++i) {
            int ig = wave * 2 + i;
            af[i] = __builtin_bit_cast(bf16x8,
                *(const u16x8*)(W2pA + (((size_t)(ig * 8 + kt)) << 9) + (lane << 3)));
        }
        #pragma unroll
        for (int j = 0; j < 4; ++j)
            bo[j] = __builtin_bit_cast(bf16x8, *(const u16x8*)(&O[(j * 16 + lr) * 280 + kt * 32 + lk * 8]));
        #pragma unroll
        for (int i = 0; i < 2; ++i)
            #pragma unroll
            for (int j = 0; j < 4; ++j)
                acc2[i][j] = __builtin_amdgcn_mfma_f32_16x16x32_bf16(af[i], bo[j], acc2[i][j], 0, 0, 0);
    }

    // ---- P4: epilogue: out[b][c][hs][ws] = 2*(proj + bproj + x) ----
    {
        int hbase = wh * 8 + SHIFT;             // token row r -> hs = (hbase + r) & 127
        int wbase = ww * 8 + SHIFT;
        #pragma unroll
        for (int i = 0; i < 2; ++i)
            #pragma unroll
            for (int rg = 0; rg < 4; ++rg) {
                int c = wave * 32 + i * 16 + lk * 4 + rg;
                float bi = bproj[c];
                size_t cb = ((size_t)(b * 256 + c)) << 14;
                #pragma unroll
                for (int j = 0; j < 4; ++j) {
                    int token = j * 16 + lr;
                    int r = token >> 3, s = token & 7;
                    int hs = (hbase + r) & 127;
                    int wc = (wbase + s) & 127;
                    size_t oi = cb + hs * 128 + wc;
                    out[oi] = 2.f * (acc2[i][j][rg] + bi + x[oi]);
                }
            }
    }
}

extern "C" void kernel_launch(void* const* d_in, const int* in_sizes, int n_in,
                              void* d_out, int out_size, void* d_ws, size_t ws_size,
                              hipStream_t stream) {
    const float* x     = (const float*)d_in[0];
    const float* g1    = (const float*)d_in[1];
    const float* bb1   = (const float*)d_in[2];
    const float* wqkv  = (const float*)d_in[3];
    const float* bqkv  = (const float*)d_in[4];
    const float* wproj = (const float*)d_in[5];
    const float* bproj = (const float*)d_in[6];
    float* out = (float*)d_out;

    char* ws = (char*)d_ws;
    u16* W2q  = (u16*)ws;                          // 384 KiB
    u16* W2pA = (u16*)(ws + 393216);               // 128 KiB
    u16* ywin = (u16*)(ws + (1ull << 20));         // 64 MiB

    static const int LDS_BYTES = 151552;
    hipFuncSetAttribute((const void*)k_fused,
                        hipFuncAttributeMaxDynamicSharedMemorySize, LDS_BYTES);

    k_prep_w<<<1024, 256, 0, stream>>>(wqkv, wproj, W2q, W2pA);
    k_ln_win<<<dim3(128, 8), 256, 0, stream>>>(x, g1, bb1, ywin);
    k_fused<<<NWIN, 512, LDS_BYTES, stream>>>(ywin, W2q, W2pA, bqkv, bproj, x, out);
}

// Round 6
// 243.799 us; speedup vs baseline: 1.5586x; 1.0700x over previous
//
#include <hip/hip_runtime.h>
#include <stdint.h>

#define SHIFT 4
#define EPS 1e-5f

#define B_ 8
#define C_ 256
#define H_ 128
#define W_ 128
#define HW_ (H_*W_)
#define NWIN 2048            // 8 * 16 * 16 windows

typedef unsigned short u16;
typedef float f32x4 __attribute__((ext_vector_type(4)));
typedef __bf16 bf16x8 __attribute__((ext_vector_type(8)));
typedef unsigned short u16x8 __attribute__((ext_vector_type(8)));
typedef unsigned short u16x4 __attribute__((ext_vector_type(4)));

static __device__ __forceinline__ u16 f2bf(float f) {
    uint32_t u = __builtin_bit_cast(uint32_t, f);
    u = u + 0x7fffu + ((u >> 16) & 1u);
    return (u16)(u >> 16);
}
static __device__ __forceinline__ float bf2f(u16 u) {
    return __builtin_bit_cast(float, (uint32_t)u << 16);
}

// ---------------- K0: weight prep into per-fragment streaming order ----------------
// W2q: qkv B-frags: [jg(48)][kt(8)][lane(64)][e(8)]  <- wqkv[k][col], col=jg*16+(l&15), k=kt*32+(l>>4)*8+e
// W2pA: proj A-frags (operand-swapped): [ig(16)][kt(8)][lane(64)][e(8)] <- wproj[k][c], c=ig*16+(l&15)
__global__ __launch_bounds__(256) void k_prep_w(const float* __restrict__ wqkv,
                                                const float* __restrict__ wproj,
                                                u16* __restrict__ W2q, u16* __restrict__ W2pA) {
    int i = blockIdx.x * 256 + threadIdx.x;   // 0 .. 262143
    if (i < 48 * 8 * 64 * 8) {
        int e = i & 7, l = (i >> 3) & 63, kt = (i >> 9) & 7, jg = i >> 12;
        int col = jg * 16 + (l & 15);
        int k = kt * 32 + (l >> 4) * 8 + e;
        W2q[i] = f2bf(wqkv[k * 768 + col]);
    } else {
        int j = i - 48 * 8 * 64 * 8;          // < 65536
        int e = j & 7, l = (j >> 3) & 63, kt = (j >> 9) & 7, ig = j >> 12;
        int c = ig * 16 + (l & 15);
        int k = kt * 32 + (l >> 4) * 8 + e;
        W2pA[j] = f2bf(wproj[k * 256 + c]);
    }
}

// ---------------- K1: LN stats + LN + shift + window partition -> frag-ordered ywin ----------------
// ywin2[win][kt(8)][i(4)][lane(64)][e(8)]: value y[token = i*16+(lane&15)][c = kt*32+(lane>>4)*8+e]
__global__ __launch_bounds__(256) void k_ln_win(const float* __restrict__ x,
                                                const float* __restrict__ g,
                                                const float* __restrict__ beta,
                                                u16* __restrict__ ywin2) {
    __shared__ u16 sv[256][130];
    __shared__ float ps[2][128];
    __shared__ float pss[2][128];
    __shared__ float mval[128];
    __shared__ float rval[128];
    int h = blockIdx.x;
    int b = blockIdx.y;
    int t = threadIdx.x;
    int p = t >> 7, w = t & 127;
    const float* xb = x + (size_t)b * C_ * HW_ + (size_t)h * W_;
    float s = 0.f, ss = 0.f;
    #pragma unroll 8
    for (int it = 0; it < 128; ++it) {
        int c = it * 2 + p;
        float v = xb[(size_t)c * HW_ + w];
        s += v; ss += v * v;
        sv[c][w] = f2bf(v);
    }
    ps[p][w] = s;
    pss[p][w] = ss;
    __syncthreads();
    if (t < 128) {
        float st = ps[0][t] + ps[1][t];
        float sst = pss[0][t] + pss[1][t];
        float m = st * (1.f / C_);
        float var = sst * (1.f / C_) - m * m;
        mval[t] = m;
        rval[t] = rsqrtf(var + EPS);
    }
    __syncthreads();
    int hp = (h - SHIFT) & 127;
    int wh = hp >> 3, r = hp & 7;
    int i_f = r >> 1;                 // token = r*8+s -> frag i
    int lrb = (r & 1) * 8;            // frag lane-row base
    int c = t;
    float gc = g[c], bc = beta[c];
    int kt = c >> 5, lk2 = (c >> 3) & 3, e = c & 7;
    int winrow = (b * 16 + wh) * 16;
    u16* dst = ywin2 + (size_t)winrow * 16384 + kt * 2048 + i_f * 512 + lk2 * 128 + lrb * 8 + e;
    #pragma unroll 4
    for (int wp = 0; wp < 128; ++wp) {
        int wsrc = (wp + SHIFT) & 127;
        float v = bf2f(sv[c][wsrc]);
        float yv = (v - mval[wsrc]) * rval[wsrc] * gc + bc;
        dst[(size_t)(wp >> 3) * 16384 + (wp & 7) * 8] = f2bf(yv);
    }
}

// ---------------- K2: MEGA: qkv + attention + proj + residual, per-wave head ownership ----------------
// 1 block = 1 window, 512 thr = 8 waves, wave = head. LDS 80 KiB -> 2 blocks/CU.
// Per-wave region 10240 B: Q[64][40] @0 | K[64][40] @2560u16; VT[32][72] overlays Q;
// Phalf[64][40] overlays K. O[64][280] overlays everything after barrier.
__global__ __launch_bounds__(512, 4) void k_fused(const u16* __restrict__ ywin2,
                                                  const u16* __restrict__ W2q,
                                                  const u16* __restrict__ W2pA,
                                                  const float* __restrict__ bqkv,
                                                  const float* __restrict__ bproj,
                                                  const float* __restrict__ x,
                                                  float* __restrict__ out) {
    extern __shared__ __align__(16) char smem[];
    int bid = blockIdx.x;
    int win = (bid & 7) * 256 + (bid >> 3);      // XCD-chunked
    int b = win >> 8, wh = (win >> 4) & 15, ww = win & 15;
    int t = threadIdx.x;
    int wave = t >> 6, lane = t & 63;
    int lr = lane & 15, lk = lane >> 4;
    int hd = wave;

    u16* WR = (u16*)smem + wave * 5120;   // u16 units
    u16* Q  = WR;
    u16* K  = WR + 2560;
    u16* VT = WR;          // overlay Q (Q dead after qf reads)
    u16* Ph = WR + 2560;   // overlay K (K dead after kf reads)
    u16* O  = (u16*)smem;  // [64][280] after barrier

    const u16* afp = ywin2 + (size_t)win * 16384;

    // ---- qk-pass: acc[i][jl], jl: 0,1=q d0/d1; 2,3=k d0/d1 ----
    f32x4 acc[4][4];
    #pragma unroll
    for (int i = 0; i < 4; ++i)
        #pragma unroll
        for (int j = 0; j < 4; ++j) acc[i][j] = (f32x4){0.f,0.f,0.f,0.f};
    #pragma unroll 2
    for (int kt = 0; kt < 8; ++kt) {
        bf16x8 af[4], bq[4];
        #pragma unroll
        for (int i = 0; i < 4; ++i)
            af[i] = __builtin_bit_cast(bf16x8, *(const u16x8*)(afp + kt * 2048 + i * 512 + lane * 8));
        #pragma unroll
        for (int jl = 0; jl < 4; ++jl) {
            int jg = (jl >> 1) * 16 + 2 * hd + (jl & 1);
            bq[jl] = __builtin_bit_cast(bf16x8, *(const u16x8*)(W2q + ((size_t)(jg * 8 + kt)) * 512 + lane * 8));
        }
        #pragma unroll
        for (int i = 0; i < 4; ++i)
            #pragma unroll
            for (int jl = 0; jl < 4; ++jl)
                acc[i][jl] = __builtin_amdgcn_mfma_f32_16x16x32_bf16(af[i], bq[jl], acc[i][jl], 0, 0, 0);
    }
    // stage Q, K (pad-40)
    #pragma unroll
    for (int jl = 0; jl < 4; ++jl) {
        int which = jl >> 1;
        int d = (jl & 1) * 16 + lr;
        float bi = bqkv[which * 256 + hd * 32 + d];
        u16* dst = which ? K : Q;
        #pragma unroll
        for (int i = 0; i < 4; ++i)
            #pragma unroll
            for (int rg = 0; rg < 4; ++rg)
                dst[(i * 16 + lk * 4 + rg) * 40 + d] = f2bf(acc[i][jl][rg] + bi);
    }
    // ---- S = Q K^T ----
    bf16x8 qf[4], kf[4];
    #pragma unroll
    for (int i = 0; i < 4; ++i)
        qf[i] = __builtin_bit_cast(bf16x8, *(const u16x8*)(&Q[(i * 16 + lr) * 40 + lk * 8]));
    #pragma unroll
    for (int j = 0; j < 4; ++j)
        kf[j] = __builtin_bit_cast(bf16x8, *(const u16x8*)(&K[(j * 16 + lr) * 40 + lk * 8]));
    f32x4 s[4][4];
    #pragma unroll
    for (int i = 0; i < 4; ++i)
        #pragma unroll
        for (int j = 0; j < 4; ++j) s[i][j] = (f32x4){0.f,0.f,0.f,0.f};
    #pragma unroll
    for (int i = 0; i < 4; ++i)
        #pragma unroll
        for (int j = 0; j < 4; ++j)
            s[i][j] = __builtin_amdgcn_mfma_f32_16x16x32_bf16(qf[i], kf[j], s[i][j], 0, 0, 0);

    // ---- softmax in-register (rows q = i*16+lk*4+rg; k over 4 regs x 16 lr-lanes) ----
    const float scale = 0.17677669529663687f;
    #pragma unroll
    for (int i = 0; i < 4; ++i) {
        #pragma unroll
        for (int rg = 0; rg < 4; ++rg) {
            float s0 = s[i][0][rg] * scale, s1 = s[i][1][rg] * scale;
            float s2 = s[i][2][rg] * scale, s3 = s[i][3][rg] * scale;
            float mx = fmaxf(fmaxf(s0, s1), fmaxf(s2, s3));
            mx = fmaxf(mx, __shfl_xor(mx, 1));
            mx = fmaxf(mx, __shfl_xor(mx, 2));
            mx = fmaxf(mx, __shfl_xor(mx, 4));
            mx = fmaxf(mx, __shfl_xor(mx, 8));
            float p0 = __expf(s0 - mx), p1 = __expf(s1 - mx);
            float p2 = __expf(s2 - mx), p3 = __expf(s3 - mx);
            float sm = p0 + p1 + p2 + p3;
            sm += __shfl_xor(sm, 1);
            sm += __shfl_xor(sm, 2);
            sm += __shfl_xor(sm, 4);
            sm += __shfl_xor(sm, 8);
            float rs = 1.f / sm;
            s[i][0][rg] = p0 * rs; s[i][1][rg] = p1 * rs;
            s[i][2][rg] = p2 * rs; s[i][3][rg] = p3 * rs;
        }
    }
    // write P half 0 (k 0..31) -> frees s[*][0..1]
    #pragma unroll
    for (int j2 = 0; j2 < 2; ++j2)
        #pragma unroll
        for (int i = 0; i < 4; ++i)
            #pragma unroll
            for (int rg = 0; rg < 4; ++rg)
                Ph[(i * 16 + lk * 4 + rg) * 40 + j2 * 16 + lr] = f2bf(s[i][j2][rg]);

    // ---- v-pass: av[i][jl] ----
    f32x4 av[4][2];
    #pragma unroll
    for (int i = 0; i < 4; ++i)
        #pragma unroll
        for (int j = 0; j < 2; ++j) av[i][j] = (f32x4){0.f,0.f,0.f,0.f};
    #pragma unroll 2
    for (int kt = 0; kt < 8; ++kt) {
        bf16x8 af[4], bv[2];
        #pragma unroll
        for (int i = 0; i < 4; ++i)
            af[i] = __builtin_bit_cast(bf16x8, *(const u16x8*)(afp + kt * 2048 + i * 512 + lane * 8));
        #pragma unroll
        for (int jl = 0; jl < 2; ++jl) {
            int jg = 32 + 2 * hd + jl;
            bv[jl] = __builtin_bit_cast(bf16x8, *(const u16x8*)(W2q + ((size_t)(jg * 8 + kt)) * 512 + lane * 8));
        }
        #pragma unroll
        for (int i = 0; i < 4; ++i)
            #pragma unroll
            for (int jl = 0; jl < 2; ++jl)
                av[i][jl] = __builtin_amdgcn_mfma_f32_16x16x32_bf16(af[i], bv[jl], av[i][jl], 0, 0, 0);
    }
    // VT[d][tok] pad-72, packed b64 writes (VT overlays Q)
    #pragma unroll
    for (int jl = 0; jl < 2; ++jl) {
        float bi = bqkv[512 + hd * 32 + jl * 16 + lr];
        #pragma unroll
        for (int i = 0; i < 4; ++i) {
            u16x4 pk;
            #pragma unroll
            for (int rg = 0; rg < 4; ++rg) pk[rg] = f2bf(av[i][jl][rg] + bi);
            *(u16x4*)(&VT[(jl * 16 + lr) * 72 + i * 16 + lk * 4]) = pk;
        }
    }
    // ---- PV, half 0 ----
    f32x4 oacc[4][2];
    #pragma unroll
    for (int i = 0; i < 4; ++i)
        #pragma unroll
        for (int j = 0; j < 2; ++j) oacc[i][j] = (f32x4){0.f,0.f,0.f,0.f};
    {
        bf16x8 pf[4], vf[2];
        #pragma unroll
        for (int i = 0; i < 4; ++i)
            pf[i] = __builtin_bit_cast(bf16x8, *(const u16x8*)(&Ph[(i * 16 + lr) * 40 + lk * 8]));
        #pragma unroll
        for (int j = 0; j < 2; ++j)
            vf[j] = __builtin_bit_cast(bf16x8, *(const u16x8*)(&VT[(j * 16 + lr) * 72 + lk * 8]));
        #pragma unroll
        for (int i = 0; i < 4; ++i)
            #pragma unroll
            for (int j = 0; j < 2; ++j)
                oacc[i][j] = __builtin_amdgcn_mfma_f32_16x16x32_bf16(pf[i], vf[j], oacc[i][j], 0, 0, 0);
    }
    // write P half 1 (k 32..63) into same Ph region (HW in-order DS; aliasing keeps order)
    #pragma unroll
    for (int j2 = 2; j2 < 4; ++j2)
        #pragma unroll
        for (int i = 0; i < 4; ++i)
            #pragma unroll
            for (int rg = 0; rg < 4; ++rg)
                Ph[(i * 16 + lk * 4 + rg) * 40 + (j2 & 1) * 16 + lr] = f2bf(s[i][j2][rg]);
    // ---- PV, half 1 ----
    {
        bf16x8 pf[4], vf[2];
        #pragma unroll
        for (int i = 0; i < 4; ++i)
            pf[i] = __builtin_bit_cast(bf16x8, *(const u16x8*)(&Ph[(i * 16 + lr) * 40 + lk * 8]));
        #pragma unroll
        for (int j = 0; j < 2; ++j)
            vf[j] = __builtin_bit_cast(bf16x8, *(const u16x8*)(&VT[(j * 16 + lr) * 72 + 32 + lk * 8]));
        #pragma unroll
        for (int i = 0; i < 4; ++i)
            #pragma unroll
            for (int j = 0; j < 2; ++j)
                oacc[i][j] = __builtin_amdgcn_mfma_f32_16x16x32_bf16(pf[i], vf[j], oacc[i][j], 0, 0, 0);
    }

    __syncthreads();   // all waves done with private regions -> O overlay safe
    // O[tok][c] pad-280
    #pragma unroll
    for (int i = 0; i < 4; ++i)
        #pragma unroll
        for (int j = 0; j < 2; ++j)
            #pragma unroll
            for (int rg = 0; rg < 4; ++rg)
                O[(i * 16 + lk * 4 + rg) * 280 + hd * 32 + j * 16 + lr] = f2bf(oacc[i][j][rg]);
    __syncthreads();

    // ---- proj (swapped): D[c][tok], wave covers c = wave*32 .. +31 ----
    f32x4 c2[2][4];
    #pragma unroll
    for (int i = 0; i < 2; ++i)
        #pragma unroll
        for (int j = 0; j < 4; ++j) c2[i][j] = (f32x4){0.f,0.f,0.f,0.f};
    #pragma unroll 2
    for (int kt = 0; kt < 8; ++kt) {
        bf16x8 a2[2], bo[4];
        #pragma unroll
        for (int i2 = 0; i2 < 2; ++i2)
            a2[i2] = __builtin_bit_cast(bf16x8,
                *(const u16x8*)(W2pA + ((size_t)((wave * 2 + i2) * 8 + kt)) * 512 + lane * 8));
        #pragma unroll
        for (int j = 0; j < 4; ++j)
            bo[j] = __builtin_bit_cast(bf16x8, *(const u16x8*)(&O[(j * 16 + lr) * 280 + kt * 32 + lk * 8]));
        #pragma unroll
        for (int i2 = 0; i2 < 2; ++i2)
            #pragma unroll
            for (int j = 0; j < 4; ++j)
                c2[i2][j] = __builtin_amdgcn_mfma_f32_16x16x32_bf16(a2[i2], bo[j], c2[i2][j], 0, 0, 0);
    }

    // ---- epilogue: out[b][c][hs][ws] = 2*(proj + bproj + x) ----
    {
        int hbase = wh * 8 + SHIFT;
        int wbase = ww * 8 + SHIFT;
        #pragma unroll
        for (int i = 0; i < 2; ++i)
            #pragma unroll
            for (int rg = 0; rg < 4; ++rg) {
                int c = wave * 32 + i * 16 + lk * 4 + rg;
                float bi = bproj[c];
                size_t cb = ((size_t)(b * 256 + c)) << 14;
                #pragma unroll
                for (int j = 0; j < 4; ++j) {
                    int token = j * 16 + lr;
                    int r = token >> 3, sgm = token & 7;
                    int hs = (hbase + r) & 127;
                    int wc = (wbase + sgm) & 127;
                    size_t oi = cb + hs * 128 + wc;
                    out[oi] = 2.f * (c2[i][j][rg] + bi + x[oi]);
                }
            }
    }
}

extern "C" void kernel_launch(void* const* d_in, const int* in_sizes, int n_in,
                              void* d_out, int out_size, void* d_ws, size_t ws_size,
                              hipStream_t stream) {
    const float* x     = (const float*)d_in[0];
    const float* g1    = (const float*)d_in[1];
    const float* bb1   = (const float*)d_in[2];
    const float* wqkv  = (const float*)d_in[3];
    const float* bqkv  = (const float*)d_in[4];
    const float* wproj = (const float*)d_in[5];
    const float* bproj = (const float*)d_in[6];
    float* out = (float*)d_out;

    char* ws = (char*)d_ws;
    u16* W2q  = (u16*)ws;                          // 384 KiB
    u16* W2pA = (u16*)(ws + 393216);               // 128 KiB
    u16* ywin2 = (u16*)(ws + (1ull << 20));        // 64 MiB frag-ordered

    static const int LDS_BYTES = 81920;
    hipFuncSetAttribute((const void*)k_fused,
                        hipFuncAttributeMaxDynamicSharedMemorySize, LDS_BYTES);

    k_prep_w<<<1024, 256, 0, stream>>>(wqkv, wproj, W2q, W2pA);
    k_ln_win<<<dim3(128, 8), 256, 0, stream>>>(x, g1, bb1, ywin2);
    k_fused<<<NWIN, 512, LDS_BYTES, stream>>>(ywin2, W2q, W2pA, bqkv, bproj, x, out);
}